// Round 1
// baseline (965.264 us; speedup 1.0000x reference)
//
#include <hip/hip_runtime.h>
#include <math.h>

#define CC    768
#define C3    2304
#define KD    2304   /* dense GEMM K: 3 chunks x 768 (fp16 3-term split) */
#define LDA2  1536   /* compact 2-split row stride: [a0(768) | a1(768)] */
#define TT    1024
#define BB    4
#define HH    12
#define HD    64
#define EE    16
#define DFFN  3072
#define NTOK  4096
#define NSLOT 8192
#define LDP   136    /* flash LDS padded stride (halves) */

typedef unsigned short u16;
typedef unsigned int   u32;
typedef __attribute__((ext_vector_type(8))) short short8;
typedef __attribute__((ext_vector_type(4))) float floatx4;

__device__ __forceinline__ u16 f2bf(float f){
  u32 x = __builtin_bit_cast(u32, f);
  x += 0x7fffu + ((x >> 16) & 1u);   // RNE
  return (u16)(x >> 16);
}
__device__ __forceinline__ u16 f2h(float f){
  _Float16 h = (_Float16)f;
  return __builtin_bit_cast(u16, h);
}
__device__ __forceinline__ float h2f(u16 u){
  return (float)__builtin_bit_cast(_Float16, u);
}
__device__ __forceinline__ float gelu_exact(float v){
  return 0.5f * v * (1.f + erff(v * 0.70710678118654752440f));
}
// x64-scaled fp16 2-way split: v*64 = h0 + h1 (+ <2^-24 rel residual)
__device__ __forceinline__ void split2h(float v, u16& h0, u16& h1){
  float vs = v * 64.f;
  h0 = f2h(vs);
  h1 = f2h(vs - h2f(h0));
}
// async global->LDS, 16B per lane, LDS dest = wave-uniform base + lane*16
__device__ __forceinline__ void gload_lds16(const void* g, void* l){
  __builtin_amdgcn_global_load_lds(
      (const __attribute__((address_space(1))) void*)g,
      (__attribute__((address_space(3))) void*)l, 16, 0, 0);
}

// ---------------- fp32 -> transpose. MODE 0: plain bf16 [z][Cn][R].
// MODE 1: fp16 2-split x64 [Cn][1536] ([b0|b1])
template<int MODE>
__global__ __launch_bounds__(256) void transpose_split(const float* __restrict__ src,
    u16* __restrict__ d0, int R, int Cn)
{
  __shared__ float tile[32][33];
  int z = blockIdx.z;
  const float* s = src + (size_t)z * R * Cn;
  int c0 = blockIdx.x * 32, r0 = blockIdx.y * 32;
  int tx = threadIdx.x & 31, ty = threadIdx.x >> 5;
  #pragma unroll
  for (int j = 0; j < 4; ++j)
    tile[ty + j*8][tx] = s[(size_t)(r0 + ty + j*8) * Cn + c0 + tx];
  __syncthreads();
  #pragma unroll
  for (int j = 0; j < 4; ++j){
    float v = tile[tx][ty + j*8];
    if (MODE == 1){
      u16 h0, h1; split2h(v, h0, h1);
      size_t base = (size_t)(c0 + ty + j*8) * LDA2 + (r0 + tx);
      d0[base] = h0; d0[base + 768] = h1;
    } else {
      d0[(size_t)z * R * Cn + (size_t)(c0 + ty + j*8) * R + r0 + tx] = f2bf(v);
    }
  }
}

// ---------------- LayerNorm. MODE 0: fp32 out + bf16 out (stride CC).
// MODE 1: fp16 2-split x64 out [tok][1536].
template<int MODE>
__global__ __launch_bounds__(256) void ln_kernel(const float* __restrict__ x,
    const float* __restrict__ gw, const float* __restrict__ gb,
    float* __restrict__ of, u16* __restrict__ o0)
{
  int tok = blockIdx.x, tid = threadIdx.x;
  const float* xr = x + (size_t)tok * CC;
  float v0 = xr[tid], v1 = xr[tid + 256], v2 = xr[tid + 512];
  __shared__ float r1[4], r2[4];
  __shared__ float mus, rss;
  float s = v0 + v1 + v2;
  #pragma unroll
  for (int off = 32; off >= 1; off >>= 1) s += __shfl_down(s, off);
  if ((tid & 63) == 0) r1[tid >> 6] = s;
  __syncthreads();
  if (tid == 0) mus = (r1[0] + r1[1] + r1[2] + r1[3]) * (1.f / 768.f);
  __syncthreads();
  float mu = mus;
  float d0 = v0 - mu, d1 = v1 - mu, d2 = v2 - mu;
  float t = d0*d0 + d1*d1 + d2*d2;
  #pragma unroll
  for (int off = 32; off >= 1; off >>= 1) t += __shfl_down(t, off);
  if ((tid & 63) == 0) r2[tid >> 6] = t;
  __syncthreads();
  if (tid == 0) rss = rsqrtf((r2[0] + r2[1] + r2[2] + r2[3]) * (1.f / 768.f) + 1e-5f);
  __syncthreads();
  float rstd = rss;
  float dv[3] = {d0, d1, d2};
  #pragma unroll
  for (int i = 0; i < 3; ++i){
    int c = tid + i * 256;
    float vv = dv[i] * rstd * gw[c] + gb[c];
    if (MODE == 1){
      u16 h0, h1; split2h(vv, h0, h1);
      o0[(size_t)tok * LDA2 + c] = h0;
      o0[(size_t)tok * LDA2 + 768 + c] = h1;
    } else {
      size_t idx = (size_t)tok * CC + c;
      of[idx] = vv;
      o0[idx] = f2bf(vv);
    }
  }
}

// ---------------- dense fp16-split NT GEMM: C[M][N] = (1/4096)*A'B' + bias + resid
// A chunks [a0,a0,a1], B chunks [b0,b1,b0]. K=2304. Prefetch double-buffered LDS:
// stage tile k+1 BEFORE computing tile k (T3-min schedule; 1 barrier per K-step).
__global__ __launch_bounds__(256) void gemm_dense(
    const u16* __restrict__ A, const u16* __restrict__ Bt,
    float* __restrict__ C, const float* __restrict__ bias,
    const float* __restrict__ resid, int N)
{
  __shared__ u16 As[2][128 * 32];
  __shared__ u16 Bs[2][128 * 32];
  int tid = threadIdx.x;
  int lane = tid & 63, wave = tid >> 6;
  int wm = wave & 1, wn = wave >> 1;
  int m0 = blockIdx.y * 128, n0 = blockIdx.x * 128;
  int ra = tid >> 2, ka = (tid & 3) * 8;
  const u16* pa0 = A  + (size_t)(m0 + ra)      * LDA2 + ka;
  const u16* pa1 = A  + (size_t)(m0 + ra + 64) * LDA2 + ka;
  const u16* pb0 = Bt + (size_t)(n0 + ra)      * LDA2 + ka;
  const u16* pb1 = Bt + (size_t)(n0 + ra + 64) * LDA2 + ka;
  floatx4 acc[4][4] = {};
  int el = lane & 15, eq = lane >> 4;

  auto stage = [&](int buf, int k0){
    int ca = (k0 >= 768) ? k0 - 768 : k0;
    int cb = (k0 < 1536) ? k0 : k0 - 1536;
    gload_lds16(pa0 + ca, &As[buf][wave*512]);
    gload_lds16(pa1 + ca, &As[buf][2048 + wave*512]);
    gload_lds16(pb0 + cb, &Bs[buf][wave*512]);
    gload_lds16(pb1 + cb, &Bs[buf][2048 + wave*512]);
  };
  stage(0, 0);
  __syncthreads();                 // vmcnt(0) drain: buf0 ready
  int cur = 0;
  for (int k0 = 0; k0 < KD; k0 += 32){
    if (k0 + 32 < KD) stage(cur ^ 1, k0 + 32);   // next tile in flight
    short8 fa[4], fb[4];
    #pragma unroll
    for (int t = 0; t < 4; ++t)
      fa[t] = *(const short8*)&As[cur][(size_t)(wm*64 + t*16 + el) * 32 + eq*8];
    #pragma unroll
    for (int t = 0; t < 4; ++t)
      fb[t] = *(const short8*)&Bs[cur][(size_t)(wn*64 + t*16 + el) * 32 + eq*8];
    #pragma unroll
    for (int mt = 0; mt < 4; ++mt)
      #pragma unroll
      for (int nt = 0; nt < 4; ++nt)
        acc[mt][nt] = __builtin_amdgcn_mfma_f32_16x16x32_f16(fa[mt], fb[nt], acc[mt][nt], 0, 0, 0);
    __syncthreads();               // drains the prefetch; next buf ready
    cur ^= 1;
  }
  const float ds = 1.f / 4096.f;
  #pragma unroll
  for (int mt = 0; mt < 4; ++mt){
    #pragma unroll
    for (int nt = 0; nt < 4; ++nt){
      int col = n0 + wn*64 + nt*16 + el;
      float bv = bias ? bias[col] : 0.f;
      #pragma unroll
      for (int r = 0; r < 4; ++r){
        int row = m0 + wm*64 + mt*16 + eq*4 + r;
        size_t idx = (size_t)row * N + col;
        float val = acc[mt][nt][r] * ds + bv;
        if (resid) val += resid[idx];
        C[idx] = val;
      }
    }
  }
}

// ---------------- MFMA flash attention (fp16 3-term split, fp32-class accuracy) ----
// grid (16 qtiles LPT, 48 bh), block 256 = 4 waves x 16 rows. Q-tile 64, K-tile 64.
// LDS 69.6 KB -> 2 blocks/CU.
__global__ __launch_bounds__(256) void flash_mfma(const float* __restrict__ qkv,
    u16* __restrict__ yH)
{
  __shared__ u16 Qs[64 * LDP];
  __shared__ u16 Ks[64 * LDP];
  __shared__ u16 Vt[64 * LDP];
  __shared__ u16 Ps[64 * LDP];
  int tid = threadIdx.x;
  int lane = tid & 63, wv = tid >> 6;
  int qi = 15 - blockIdx.x;              // big tiles dispatch first (LPT)
  int bh = blockIdx.y;
  int b = bh / HH, h = bh % HH;
  int el = lane & 15, eq = lane >> 4;
  int m0 = wv * 16;
  int row0 = qi * 64;

  // stage Q (x64 fp16 2-split): thread -> row tid>>2 (wave-private rows!)
  {
    int r = tid >> 2, d0 = (tid & 3) * 16;
    const float* src = qkv + (size_t)(b*TT + row0 + r) * C3 + h*HD + d0;
    u16* q0 = &Qs[r * LDP + d0];
    #pragma unroll
    for (int i = 0; i < 16; i += 2){
      u16 a0, a1, b0, b1;
      split2h(src[i], a0, a1);
      split2h(src[i+1], b0, b1);
      *(u32*)&q0[i]      = (u32)a0 | ((u32)b0 << 16);
      *(u32*)&q0[64 + i] = (u32)a1 | ((u32)b1 << 16);
    }
  }
  floatx4 O[4] = {};
  float mrow[4], lrow[4];
  #pragma unroll
  for (int r = 0; r < 4; ++r){ mrow[r] = -1e30f; lrow[r] = 0.f; }

  const float cmul = 0.125f * 1.44269504088896340736f / 4096.f; // descale + ln->log2
  const int ABase[6] = {0,32,0,32,64,96};
  const int BBase[6] = {0,32,64,96,0,32};

  for (int kt = 0; kt <= qi; ++kt){
    __syncthreads();
    { // stage K [key][k0|k1]: thread -> key tid>>2, dims (tid&3)*16..+15
      int j = tid >> 2, d0 = (tid & 3) * 16;
      const float* src = qkv + (size_t)(b*TT + kt*64 + j) * C3 + CC + h*HD + d0;
      u16* kp = &Ks[j * LDP + d0];
      #pragma unroll
      for (int i = 0; i < 16; i += 2){
        u16 a0, a1, b0, b1;
        split2h(src[i], a0, a1);
        split2h(src[i+1], b0, b1);
        *(u32*)&kp[i]      = (u32)a0 | ((u32)b0 << 16);
        *(u32*)&kp[64 + i] = (u32)a1 | ((u32)b1 << 16);
      }
      // stage V transposed [dim][v0|v1]: thread -> dim tid&63, keys (tid>>6)*16..+15
      int d = tid & 63, kp0 = (tid >> 6) * 16;
      const float* vsrc = qkv + (size_t)(b*TT + kt*64 + kp0) * C3 + 2*CC + h*HD + d;
      u16* vt = &Vt[d * LDP];
      #pragma unroll
      for (int i = 0; i < 16; i += 2){
        u16 a0, a1, b0, b1;
        split2h(vsrc[(size_t)i * C3], a0, a1);
        split2h(vsrc[(size_t)(i+1) * C3], b0, b1);
        *(u32*)&vt[kp0 + i]      = (u32)a0 | ((u32)b0 << 16);
        *(u32*)&vt[64 + kp0 + i] = (u32)a1 | ((u32)b1 << 16);
      }
    }
    __syncthreads();
    // S = Q K^T (x4096)
    floatx4 S[4] = {};
    #pragma unroll
    for (int ks = 0; ks < 6; ++ks){
      short8 fa = *(const short8*)&Qs[(m0 + el) * LDP + ABase[ks] + eq*8];
      short8 fb[4];
      #pragma unroll
      for (int nt = 0; nt < 4; ++nt)
        fb[nt] = *(const short8*)&Ks[(nt*16 + el) * LDP + BBase[ks] + eq*8];
      #pragma unroll
      for (int nt = 0; nt < 4; ++nt)
        S[nt] = __builtin_amdgcn_mfma_f32_16x16x32_f16(fa, fb[nt], S[nt], 0, 0, 0);
    }
    // mask + online softmax (16 rows per wave; m row-uniform via shfl over el)
    #pragma unroll
    for (int nt = 0; nt < 4; ++nt){
      int kcol = kt*64 + nt*16 + el;
      #pragma unroll
      for (int r = 0; r < 4; ++r){
        int grow = row0 + m0 + eq*4 + r;
        float sv = S[nt][r] * cmul;
        S[nt][r] = (kcol <= grow) ? sv : -1e30f;
      }
    }
    #pragma unroll
    for (int r = 0; r < 4; ++r){
      float tmax = fmaxf(fmaxf(S[0][r], S[1][r]), fmaxf(S[2][r], S[3][r]));
      #pragma unroll
      for (int off = 1; off < 16; off <<= 1) tmax = fmaxf(tmax, __shfl_xor(tmax, off));
      float mnew = fmaxf(mrow[r], tmax);
      float al = exp2f(mrow[r] - mnew);
      mrow[r] = mnew;
      lrow[r] *= al;
      #pragma unroll
      for (int nt = 0; nt < 4; ++nt) O[nt][r] *= al;
      #pragma unroll
      for (int nt = 0; nt < 4; ++nt){
        float p = exp2f(S[nt][r] - mnew);
        lrow[r] += p;
        S[nt][r] = p;
      }
    }
    // write P (x64, 2-split) into wave-private Ps rows
    #pragma unroll
    for (int nt = 0; nt < 4; ++nt){
      #pragma unroll
      for (int r = 0; r < 4; ++r){
        u16 p0, p1; split2h(S[nt][r], p0, p1);
        int rowl = m0 + eq*4 + r;
        Ps[rowl * LDP + nt*16 + el] = p0;
        Ps[rowl * LDP + 64 + nt*16 + el] = p1;
      }
    }
    // O += P V (P x64, V x64)
    #pragma unroll
    for (int ks = 0; ks < 6; ++ks){
      short8 fa = *(const short8*)&Ps[(m0 + el) * LDP + ABase[ks] + eq*8];
      short8 fb[4];
      #pragma unroll
      for (int nt = 0; nt < 4; ++nt)
        fb[nt] = *(const short8*)&Vt[(nt*16 + el) * LDP + BBase[ks] + eq*8];
      #pragma unroll
      for (int nt = 0; nt < 4; ++nt)
        O[nt] = __builtin_amdgcn_mfma_f32_16x16x32_f16(fa, fb[nt], O[nt], 0, 0, 0);
    }
  }
  // epilogue: reduce l over el lanes, normalize (O is x4096), write yH 2-split
  #pragma unroll
  for (int r = 0; r < 4; ++r){
    float l = lrow[r];
    #pragma unroll
    for (int off = 1; off < 16; off <<= 1) l += __shfl_xor(l, off);
    float inv = 1.f / (l * 4096.f);
    int grow = row0 + m0 + eq*4 + r;
    u16* dst = yH + (size_t)(b*TT + grow) * LDA2 + h*HD;
    #pragma unroll
    for (int nt = 0; nt < 4; ++nt){
      float yv = O[nt][r] * inv;
      u16 y0, y1; split2h(yv, y0, y1);
      dst[nt*16 + el] = y0;
      dst[768 + nt*16 + el] = y1;
    }
  }
}

// ---------------- router: fp32 logits, softmax, top-2 ----------------
__global__ __launch_bounds__(256) void router_kernel(const float* __restrict__ xn2,
    const float* __restrict__ Wr, int* __restrict__ eids, float* __restrict__ wts)
{
  int wave = threadIdx.x >> 6, lane = threadIdx.x & 63;
  int tok = blockIdx.x * 4 + wave;
  int g = lane >> 4, e = lane & 15;
  const float* xr = xn2 + (size_t)tok * CC;
  float s = 0.f;
  for (int c4 = 0; c4 < 192; ++c4){
    int c = c4 * 4 + g;
    s += xr[c] * Wr[c * EE + e];
  }
  s += __shfl_xor(s, 16);
  s += __shfl_xor(s, 32);
  float mx = s;
  #pragma unroll
  for (int off = 1; off < 16; off <<= 1) mx = fmaxf(mx, __shfl_xor(mx, off));
  float p = expf(s - mx);
  float Z = p;
  #pragma unroll
  for (int off = 1; off < 16; off <<= 1) Z += __shfl_xor(Z, off);
  p /= Z;
  float best = -1.f; int bi = 0;
  for (int ee = 0; ee < 16; ++ee){
    float pe = __shfl(p, ee);
    if (pe > best){ best = pe; bi = ee; }
  }
  float sec = -1.f; int si = 0;
  for (int ee = 0; ee < 16; ++ee){
    float pe = __shfl(p, ee);
    if (ee != bi && pe > sec){ sec = pe; si = ee; }
  }
  if (lane == 0){
    eids[tok*2] = bi;  eids[tok*2+1] = si;
    wts [tok*2] = best; wts[tok*2+1] = sec;
  }
}

__global__ __launch_bounds__(256) void moe_count(const int* __restrict__ eids,
    int* __restrict__ counts, int* __restrict__ offs, int* __restrict__ curs)
{
  __shared__ int lc[EE];
  int tid = threadIdx.x;
  if (tid < EE) lc[tid] = 0;
  __syncthreads();
  for (int i = tid; i < NSLOT; i += 256) atomicAdd(&lc[eids[i]], 1);
  __syncthreads();
  if (tid == 0){
    int run = 0;
    for (int e = 0; e < EE; ++e){
      counts[e] = lc[e]; offs[e] = run; curs[e] = run; run += lc[e];
    }
    offs[EE] = run;
  }
}

__global__ __launch_bounds__(256) void moe_scatter(const int* __restrict__ eids,
    const float* __restrict__ wts, int* __restrict__ curs,
    int* __restrict__ rowmap, float* __restrict__ wgtm)
{
  int i = blockIdx.x * 256 + threadIdx.x;
  int e = eids[i];
  int pos = atomicAdd(&curs[e], 1);
  rowmap[pos] = i >> 1;
  wgtm[pos] = wts[i];
}

__global__ __launch_bounds__(256) void add2(const float* __restrict__ a,
    const float* __restrict__ b, float* __restrict__ o, int n)
{
  int i = blockIdx.x * 256 + threadIdx.x;
  if (i < n) o[i] = a[i] + b[i];
}

// ---------------- MoE expert GEMM1: H = gelu(gather(xn2b) @ W1t^T + b1) --------------
// Prefetch double-buffered (T3-min): stage k+1 before computing k, 1 barrier/step.
__global__ __launch_bounds__(256) void gemm_moe1(
    const u16* __restrict__ Xb, const u16* __restrict__ W1t, const float* __restrict__ b1,
    u16* __restrict__ H, const int* __restrict__ counts, const int* __restrict__ offs,
    const int* __restrict__ rowmap)
{
  int e = blockIdx.z;
  int cnt = counts[e];
  int m0 = blockIdx.y * 128;
  if (m0 >= cnt) return;
  int off = offs[e];
  int n0 = blockIdx.x * 128;
  const u16* Bt = W1t + (size_t)e * DFFN * CC;
  __shared__ u16 As[2][128 * 32];
  __shared__ u16 Bs[2][128 * 32];
  int tid = threadIdx.x;
  int lane = tid & 63, wave = tid >> 6;
  int wm = wave & 1, wn = wave >> 1;
  int ra = tid >> 2, ka = (tid & 3) * 8;
  int r0 = m0 + ra, r1i = m0 + ra + 64;
  int rr0 = (r0  < cnt) ? r0  : cnt - 1;   // clamp: rows >= cnt discarded in epilogue
  int rr1 = (r1i < cnt) ? r1i : cnt - 1;
  const u16* pa0 = Xb + (size_t)rowmap[off + rr0] * CC + ka;
  const u16* pa1 = Xb + (size_t)rowmap[off + rr1] * CC + ka;
  const u16* pb0 = Bt + (size_t)(n0 + ra)      * CC + ka;
  const u16* pb1 = Bt + (size_t)(n0 + ra + 64) * CC + ka;
  floatx4 acc[4][4] = {};
  int el = lane & 15, eq = lane >> 4;

  auto stage = [&](int buf, int k0){
    gload_lds16(pa0 + k0, &As[buf][wave*512]);
    gload_lds16(pa1 + k0, &As[buf][2048 + wave*512]);
    gload_lds16(pb0 + k0, &Bs[buf][wave*512]);
    gload_lds16(pb1 + k0, &Bs[buf][2048 + wave*512]);
  };
  stage(0, 0);
  __syncthreads();
  int cur = 0;
  for (int k0 = 0; k0 < CC; k0 += 32){
    if (k0 + 32 < CC) stage(cur ^ 1, k0 + 32);
    short8 fa[4], fb[4];
    #pragma unroll
    for (int t = 0; t < 4; ++t)
      fa[t] = *(const short8*)&As[cur][(size_t)(wm*64 + t*16 + el) * 32 + eq*8];
    #pragma unroll
    for (int t = 0; t < 4; ++t)
      fb[t] = *(const short8*)&Bs[cur][(size_t)(wn*64 + t*16 + el) * 32 + eq*8];
    #pragma unroll
    for (int mt = 0; mt < 4; ++mt)
      #pragma unroll
      for (int nt = 0; nt < 4; ++nt)
        acc[mt][nt] = __builtin_amdgcn_mfma_f32_16x16x32_bf16(fa[mt], fb[nt], acc[mt][nt], 0, 0, 0);
    __syncthreads();
    cur ^= 1;
  }
  #pragma unroll
  for (int mt = 0; mt < 4; ++mt){
    #pragma unroll
    for (int nt = 0; nt < 4; ++nt){
      int col = n0 + wn*64 + nt*16 + el;
      float bv = b1[(size_t)e * DFFN + col];
      #pragma unroll
      for (int r = 0; r < 4; ++r){
        int row = m0 + wm*64 + mt*16 + eq*4 + r;
        if (row < cnt)
          H[(size_t)(off + row) * DFFN + col] = f2bf(gelu_exact(acc[mt][nt][r] + bv));
      }
    }
  }
}

// ---------------- MoE expert GEMM2 (K-split x2): out[tok] += w * (H @ W2t^T + b2) ----
// Prefetch double-buffered (T3-min).
#define KSPL 2
__global__ __launch_bounds__(256) void gemm_moe2(
    const u16* __restrict__ H, const u16* __restrict__ W2t, const float* __restrict__ b2,
    float* __restrict__ Out, const int* __restrict__ counts, const int* __restrict__ offs,
    const int* __restrict__ rowmap, const float* __restrict__ wgtm)
{
  int e = blockIdx.z;
  int cnt = counts[e];
  int m0 = blockIdx.y * 128;
  if (m0 >= cnt) return;
  int off = offs[e];
  int bx = blockIdx.x;
  int n0 = (bx % 6) * 128;
  int ksp = bx / 6;
  const u16* Bt = W2t + (size_t)e * CC * DFFN;
  __shared__ u16 As[2][128 * 32];
  __shared__ u16 Bs[2][128 * 32];
  int tid = threadIdx.x;
  int lane = tid & 63, wave = tid >> 6;
  int wm = wave & 1, wn = wave >> 1;
  int ra = tid >> 2, ka = (tid & 3) * 8;
  int r0 = m0 + ra, r1i = m0 + ra + 64;
  int rr0 = (r0  < cnt) ? r0  : cnt - 1;
  int rr1 = (r1i < cnt) ? r1i : cnt - 1;
  const u16* pa0 = H + (size_t)(off + rr0) * DFFN + ka;
  const u16* pa1 = H + (size_t)(off + rr1) * DFFN + ka;
  const u16* pb0 = Bt + (size_t)(n0 + ra)      * DFFN + ka;
  const u16* pb1 = Bt + (size_t)(n0 + ra + 64) * DFFN + ka;
  floatx4 acc[4][4] = {};
  int el = lane & 15, eq = lane >> 4;
  int kbeg = ksp * (DFFN / KSPL), kend = kbeg + DFFN / KSPL;

  auto stage = [&](int buf, int k0){
    gload_lds16(pa0 + k0, &As[buf][wave*512]);
    gload_lds16(pa1 + k0, &As[buf][2048 + wave*512]);
    gload_lds16(pb0 + k0, &Bs[buf][wave*512]);
    gload_lds16(pb1 + k0, &Bs[buf][2048 + wave*512]);
  };
  stage(0, kbeg);
  __syncthreads();
  int cur = 0;
  for (int k0 = kbeg; k0 < kend; k0 += 32){
    if (k0 + 32 < kend) stage(cur ^ 1, k0 + 32);
    short8 fa[4], fb[4];
    #pragma unroll
    for (int t = 0; t < 4; ++t)
      fa[t] = *(const short8*)&As[cur][(size_t)(wm*64 + t*16 + el) * 32 + eq*8];
    #pragma unroll
    for (int t = 0; t < 4; ++t)
      fb[t] = *(const short8*)&Bs[cur][(size_t)(wn*64 + t*16 + el) * 32 + eq*8];
    #pragma unroll
    for (int mt = 0; mt < 4; ++mt)
      #pragma unroll
      for (int nt = 0; nt < 4; ++nt)
        acc[mt][nt] = __builtin_amdgcn_mfma_f32_16x16x32_bf16(fa[mt], fb[nt], acc[mt][nt], 0, 0, 0);
    __syncthreads();
    cur ^= 1;
  }
  #pragma unroll
  for (int mt = 0; mt < 4; ++mt){
    #pragma unroll
    for (int nt = 0; nt < 4; ++nt){
      int col = n0 + wn*64 + nt*16 + el;
      float bv = (ksp == 0) ? b2[(size_t)e * CC + col] : 0.f;
      #pragma unroll
      for (int r = 0; r < 4; ++r){
        int row = m0 + wm*64 + mt*16 + eq*4 + r;
        if (row < cnt){
          int slot = off + row;
          int tok = rowmap[slot];
          float wv = wgtm[slot];
          atomicAdd(&Out[(size_t)tok * CC + col], wv * (acc[mt][nt][r] + bv));
        }
      }
    }
  }
}

// =====================================================================================
extern "C" void kernel_launch(void* const* d_in, const int* in_sizes, int n_in,
                              void* d_out, int out_size, void* d_ws, size_t ws_size,
                              hipStream_t stream)
{
  const float* x     = (const float*)d_in[0];
  const float* ln1w  = (const float*)d_in[1];
  const float* ln1b  = (const float*)d_in[2];
  const float* Wattn = (const float*)d_in[3];
  const float* battn = (const float*)d_in[4];
  const float* Wproj = (const float*)d_in[5];
  const float* bproj = (const float*)d_in[6];
  const float* ln2w  = (const float*)d_in[7];
  const float* ln2b  = (const float*)d_in[8];
  const float* Wrout = (const float*)d_in[9];
  const float* W1    = (const float*)d_in[10];
  const float* b1    = (const float*)d_in[11];
  const float* W2    = (const float*)d_in[12];
  const float* b2    = (const float*)d_in[13];
  float* out = (float*)d_out;

  char* w = (char*)d_ws;
  auto alloc = [&](size_t bytes)->char* {
    char* p = w; w += (bytes + 255) & ~(size_t)255; return p;
  };
  u16* watp  = (u16*)alloc((size_t)C3 * LDA2 * 2);      //  7.1 MB  fp16 2-split [N][1536]
  u16* wptp  = (u16*)alloc((size_t)CC * LDA2 * 2);      //  2.4 MB
  u16* w1t   = (u16*)alloc((size_t)EE * DFFN * CC * 2); // 75.5 MB  bf16
  u16* w2t   = (u16*)alloc((size_t)EE * CC * DFFN * 2); // 75.5 MB
  u16* xH    = (u16*)alloc((size_t)NTOK * LDA2 * 2);    // 12.6 MB  LN1 out, fp16 2-split
  float* qkv = (float*)alloc((size_t)NTOK * C3 * 4);    // 37.7 MB
  u16* yH    = (u16*)alloc((size_t)NTOK * LDA2 * 2);    // 12.6 MB  attn out, fp16 2-split
  u16* Hbuf  = (u16*)alloc((size_t)NSLOT * DFFN * 2);   // 50.3 MB
  float* x2    = (float*)alloc((size_t)NTOK * CC * 4);
  float* xn2   = (float*)alloc((size_t)NTOK * CC * 4);
  u16*   xn2b  = (u16*)alloc((size_t)NTOK * CC * 2);
  int*   eids  = (int*)alloc(NSLOT * 4);
  float* wts   = (float*)alloc(NSLOT * 4);
  int* counts  = (int*)alloc(256);
  int* offs    = (int*)alloc(256);
  int* curs    = (int*)alloc(256);
  int* rowmap  = (int*)alloc(NSLOT * 4);
  float* wgtm  = (float*)alloc(NSLOT * 4);

  // 1) weight conversion
  hipLaunchKernelGGL((transpose_split<1>), dim3(C3/32, CC/32, 1), dim3(256), 0, stream,
                     Wattn, watp, CC, C3);
  hipLaunchKernelGGL((transpose_split<1>), dim3(CC/32, CC/32, 1), dim3(256), 0, stream,
                     Wproj, wptp, CC, CC);
  hipLaunchKernelGGL((transpose_split<0>), dim3(DFFN/32, CC/32, EE), dim3(256), 0, stream,
                     W1, w1t, CC, DFFN);
  hipLaunchKernelGGL((transpose_split<0>), dim3(CC/32, DFFN/32, EE), dim3(256), 0, stream,
                     W2, w2t, DFFN, CC);
  // 2) LN1 -> fp16 2-split xH
  hipLaunchKernelGGL((ln_kernel<1>), dim3(NTOK), dim3(256), 0, stream,
                     x, ln1w, ln1b, (float*)nullptr, xH);
  // 3) qkv = xn @ W_attn + b_attn (single K=2304 fp16 3-term pass, prefetch staging)
  hipLaunchKernelGGL(gemm_dense, dim3(C3/128, NTOK/128), dim3(256), 0, stream,
                     xH, watp, qkv, battn, (const float*)nullptr, C3);
  // 4) MFMA flash attention (Q-tile 64, 2 blocks/CU) -> yH (fp16 2-split)
  hipLaunchKernelGGL(flash_mfma, dim3(16, BB*HH), dim3(256), 0, stream, qkv, yH);
  // 5) x2 = x + y @ W_proj + b_proj (residual folded into epilogue)
  hipLaunchKernelGGL(gemm_dense, dim3(CC/128, NTOK/128), dim3(256), 0, stream,
                     yH, wptp, x2, bproj, x, CC);
  // 6) LN2 -> xn2 fp32 (router) + bf16 (MoE input)
  hipLaunchKernelGGL((ln_kernel<0>), dim3(NTOK), dim3(256), 0, stream,
                     x2, ln2w, ln2b, xn2, xn2b);
  // 7) router + expert gather lists
  hipLaunchKernelGGL(router_kernel, dim3(NTOK/4), dim3(256), 0, stream, xn2, Wrout, eids, wts);
  hipLaunchKernelGGL(moe_count, dim3(1), dim3(256), 0, stream, eids, counts, offs, curs);
  hipLaunchKernelGGL(moe_scatter, dim3(NSLOT/256), dim3(256), 0, stream, eids, wts, curs, rowmap, wgtm);
  // 8) out = x2 + xn2
  hipLaunchKernelGGL(add2, dim3(NTOK*CC/256), dim3(256), 0, stream, x2, xn2, out, NTOK*CC);
  // 9) MoE expert FFN
  hipLaunchKernelGGL(gemm_moe1, dim3(DFFN/128, 32, EE), dim3(256), 0, stream,
                     xn2b, w1t, b1, Hbuf, counts, offs, rowmap);
  hipLaunchKernelGGL(gemm_moe2, dim3(6*KSPL, 32, EE), dim3(256), 0, stream,
                     Hbuf, w2t, b2, out, counts, offs, rowmap, wgtm);
}

// Round 2
// 954.106 us; speedup vs baseline: 1.0117x; 1.0117x over previous
//
#include <hip/hip_runtime.h>
#include <math.h>

#define CC    768
#define C3    2304
#define KD    2304   /* dense GEMM K: 3 chunks x 768 (fp16 3-term split) */
#define LDA2  1536   /* compact 2-split row stride: [a0(768) | a1(768)] */
#define TT    1024
#define BB    4
#define HH    12
#define HD    64
#define EE    16
#define DFFN  3072
#define NTOK  4096
#define NSLOT 8192
#define LDP   136    /* flash LDS padded stride (halves) */

typedef unsigned short u16;
typedef unsigned int   u32;
typedef __attribute__((ext_vector_type(8))) short short8;
typedef __attribute__((ext_vector_type(4))) float floatx4;

__device__ __forceinline__ u16 f2bf(float f){
  u32 x = __builtin_bit_cast(u32, f);
  x += 0x7fffu + ((x >> 16) & 1u);   // RNE
  return (u16)(x >> 16);
}
__device__ __forceinline__ u16 f2h(float f){
  _Float16 h = (_Float16)f;
  return __builtin_bit_cast(u16, h);
}
__device__ __forceinline__ float h2f(u16 u){
  return (float)__builtin_bit_cast(_Float16, u);
}
__device__ __forceinline__ float gelu_exact(float v){
  return 0.5f * v * (1.f + erff(v * 0.70710678118654752440f));
}
// x64-scaled fp16 2-way split: v*64 = h0 + h1 (+ <2^-24 rel residual)
__device__ __forceinline__ void split2h(float v, u16& h0, u16& h1){
  float vs = v * 64.f;
  h0 = f2h(vs);
  h1 = f2h(vs - h2f(h0));
}
// async global->LDS, 16B per lane, LDS dest = wave-uniform base + lane*16
__device__ __forceinline__ void gload_lds16(const void* g, void* l){
  __builtin_amdgcn_global_load_lds(
      (const __attribute__((address_space(1))) void*)g,
      (__attribute__((address_space(3))) void*)l, 16, 0, 0);
}

// T4 pipeline fences: counted vmcnt + raw barrier (memory-clobbered so LDS
// accesses cannot cross at compile time).
#define PIPE_WAIT_STEADY  asm volatile("s_waitcnt vmcnt(4) lgkmcnt(0)" ::: "memory")
#define PIPE_WAIT_LAST    asm volatile("s_waitcnt vmcnt(0) lgkmcnt(0)" ::: "memory")
#define PIPE_BARRIER      asm volatile("s_barrier" ::: "memory")

// ---------------- fp32 -> transpose. MODE 0: plain bf16 [z][Cn][R].
// MODE 1: fp16 2-split x64 [Cn][1536] ([b0|b1])
template<int MODE>
__global__ __launch_bounds__(256) void transpose_split(const float* __restrict__ src,
    u16* __restrict__ d0, int R, int Cn)
{
  __shared__ float tile[32][33];
  int z = blockIdx.z;
  const float* s = src + (size_t)z * R * Cn;
  int c0 = blockIdx.x * 32, r0 = blockIdx.y * 32;
  int tx = threadIdx.x & 31, ty = threadIdx.x >> 5;
  #pragma unroll
  for (int j = 0; j < 4; ++j)
    tile[ty + j*8][tx] = s[(size_t)(r0 + ty + j*8) * Cn + c0 + tx];
  __syncthreads();
  #pragma unroll
  for (int j = 0; j < 4; ++j){
    float v = tile[tx][ty + j*8];
    if (MODE == 1){
      u16 h0, h1; split2h(v, h0, h1);
      size_t base = (size_t)(c0 + ty + j*8) * LDA2 + (r0 + tx);
      d0[base] = h0; d0[base + 768] = h1;
    } else {
      d0[(size_t)z * R * Cn + (size_t)(c0 + ty + j*8) * R + r0 + tx] = f2bf(v);
    }
  }
}

// ---------------- LayerNorm. MODE 0: fp32 out + bf16 out (stride CC).
// MODE 1: fp16 2-split x64 out [tok][1536].
template<int MODE>
__global__ __launch_bounds__(256) void ln_kernel(const float* __restrict__ x,
    const float* __restrict__ gw, const float* __restrict__ gb,
    float* __restrict__ of, u16* __restrict__ o0)
{
  int tok = blockIdx.x, tid = threadIdx.x;
  const float* xr = x + (size_t)tok * CC;
  float v0 = xr[tid], v1 = xr[tid + 256], v2 = xr[tid + 512];
  __shared__ float r1[4], r2[4];
  __shared__ float mus, rss;
  float s = v0 + v1 + v2;
  #pragma unroll
  for (int off = 32; off >= 1; off >>= 1) s += __shfl_down(s, off);
  if ((tid & 63) == 0) r1[tid >> 6] = s;
  __syncthreads();
  if (tid == 0) mus = (r1[0] + r1[1] + r1[2] + r1[3]) * (1.f / 768.f);
  __syncthreads();
  float mu = mus;
  float d0 = v0 - mu, d1 = v1 - mu, d2 = v2 - mu;
  float t = d0*d0 + d1*d1 + d2*d2;
  #pragma unroll
  for (int off = 32; off >= 1; off >>= 1) t += __shfl_down(t, off);
  if ((tid & 63) == 0) r2[tid >> 6] = t;
  __syncthreads();
  if (tid == 0) rss = rsqrtf((r2[0] + r2[1] + r2[2] + r2[3]) * (1.f / 768.f) + 1e-5f);
  __syncthreads();
  float rstd = rss;
  float dv[3] = {d0, d1, d2};
  #pragma unroll
  for (int i = 0; i < 3; ++i){
    int c = tid + i * 256;
    float vv = dv[i] * rstd * gw[c] + gb[c];
    if (MODE == 1){
      u16 h0, h1; split2h(vv, h0, h1);
      o0[(size_t)tok * LDA2 + c] = h0;
      o0[(size_t)tok * LDA2 + 768 + c] = h1;
    } else {
      size_t idx = (size_t)tok * CC + c;
      of[idx] = vv;
      o0[idx] = f2bf(vv);
    }
  }
}

// ---------------- dense fp16-split NT GEMM: C[M][N] = (1/4096)*A'B' + bias + resid
// A chunks [a0,a0,a1], B chunks [b0,b1,b0]. K=2304.
// T4 depth-2 pipeline: 3 LDS buffers, stage(i+2) in flight, counted vmcnt(4),
// raw s_barrier (no vmcnt(0) drain in main loop).
__global__ __launch_bounds__(256) void gemm_dense(
    const u16* __restrict__ A, const u16* __restrict__ Bt,
    float* __restrict__ C, const float* __restrict__ bias,
    const float* __restrict__ resid, int N)
{
  __shared__ u16 As[3][128 * 32];
  __shared__ u16 Bs[3][128 * 32];
  int tid = threadIdx.x;
  int lane = tid & 63, wave = tid >> 6;
  int wm = wave & 1, wn = wave >> 1;
  int m0 = blockIdx.y * 128, n0 = blockIdx.x * 128;
  int ra = tid >> 2, ka = (tid & 3) * 8;
  const u16* pa0 = A  + (size_t)(m0 + ra)      * LDA2 + ka;
  const u16* pa1 = A  + (size_t)(m0 + ra + 64) * LDA2 + ka;
  const u16* pb0 = Bt + (size_t)(n0 + ra)      * LDA2 + ka;
  const u16* pb1 = Bt + (size_t)(n0 + ra + 64) * LDA2 + ka;
  floatx4 acc[4][4] = {};
  int el = lane & 15, eq = lane >> 4;

  auto stage = [&](int buf, int k0){
    int ca = (k0 >= 768) ? k0 - 768 : k0;
    int cb = (k0 < 1536) ? k0 : k0 - 1536;
    gload_lds16(pa0 + ca, &As[buf][wave*512]);
    gload_lds16(pa1 + ca, &As[buf][2048 + wave*512]);
    gload_lds16(pb0 + cb, &Bs[buf][wave*512]);
    gload_lds16(pb1 + cb, &Bs[buf][2048 + wave*512]);
  };
  const int nsteps = KD / 32;        // 72
  stage(0, 0);
  stage(1, 32);
  int cur = 0;
  for (int i = 0; i < nsteps; ++i){
    __builtin_amdgcn_sched_barrier(0);
    if (i + 1 < nsteps) PIPE_WAIT_STEADY; else PIPE_WAIT_LAST;
    PIPE_BARRIER;
    if (i + 2 < nsteps){
      int nx = cur + 2; if (nx >= 3) nx -= 3;
      stage(nx, (i + 2) * 32);
    }
    short8 fa[4], fb[4];
    #pragma unroll
    for (int t = 0; t < 4; ++t)
      fa[t] = *(const short8*)&As[cur][(size_t)(wm*64 + t*16 + el) * 32 + eq*8];
    #pragma unroll
    for (int t = 0; t < 4; ++t)
      fb[t] = *(const short8*)&Bs[cur][(size_t)(wn*64 + t*16 + el) * 32 + eq*8];
    #pragma unroll
    for (int mt = 0; mt < 4; ++mt)
      #pragma unroll
      for (int nt = 0; nt < 4; ++nt)
        acc[mt][nt] = __builtin_amdgcn_mfma_f32_16x16x32_f16(fa[mt], fb[nt], acc[mt][nt], 0, 0, 0);
    cur = (cur == 2) ? 0 : cur + 1;
  }
  const float ds = 1.f / 4096.f;
  #pragma unroll
  for (int mt = 0; mt < 4; ++mt){
    #pragma unroll
    for (int nt = 0; nt < 4; ++nt){
      int col = n0 + wn*64 + nt*16 + el;
      float bv = bias ? bias[col] : 0.f;
      #pragma unroll
      for (int r = 0; r < 4; ++r){
        int row = m0 + wm*64 + mt*16 + eq*4 + r;
        size_t idx = (size_t)row * N + col;
        float val = acc[mt][nt][r] * ds + bv;
        if (resid) val += resid[idx];
        C[idx] = val;
      }
    }
  }
}

// ---------------- MFMA flash attention (fp16 3-term split, fp32-class accuracy) ----
// grid (16 qtiles LPT, 48 bh), block 256 = 4 waves x 16 rows. Q-tile 64, K-tile 64.
// LDS 69.6 KB -> 2 blocks/CU.
__global__ __launch_bounds__(256) void flash_mfma(const float* __restrict__ qkv,
    u16* __restrict__ yH)
{
  __shared__ u16 Qs[64 * LDP];
  __shared__ u16 Ks[64 * LDP];
  __shared__ u16 Vt[64 * LDP];
  __shared__ u16 Ps[64 * LDP];
  int tid = threadIdx.x;
  int lane = tid & 63, wv = tid >> 6;
  int qi = 15 - blockIdx.x;              // big tiles dispatch first (LPT)
  int bh = blockIdx.y;
  int b = bh / HH, h = bh % HH;
  int el = lane & 15, eq = lane >> 4;
  int m0 = wv * 16;
  int row0 = qi * 64;

  // stage Q (x64 fp16 2-split): thread -> row tid>>2 (wave-private rows!)
  {
    int r = tid >> 2, d0 = (tid & 3) * 16;
    const float* src = qkv + (size_t)(b*TT + row0 + r) * C3 + h*HD + d0;
    u16* q0 = &Qs[r * LDP + d0];
    #pragma unroll
    for (int i = 0; i < 16; i += 2){
      u16 a0, a1, b0, b1;
      split2h(src[i], a0, a1);
      split2h(src[i+1], b0, b1);
      *(u32*)&q0[i]      = (u32)a0 | ((u32)b0 << 16);
      *(u32*)&q0[64 + i] = (u32)a1 | ((u32)b1 << 16);
    }
  }
  floatx4 O[4] = {};
  float mrow[4], lrow[4];
  #pragma unroll
  for (int r = 0; r < 4; ++r){ mrow[r] = -1e30f; lrow[r] = 0.f; }

  const float cmul = 0.125f * 1.44269504088896340736f / 4096.f; // descale + ln->log2
  const int ABase[6] = {0,32,0,32,64,96};
  const int BBase[6] = {0,32,64,96,0,32};

  for (int kt = 0; kt <= qi; ++kt){
    __syncthreads();
    { // stage K [key][k0|k1]: thread -> key tid>>2, dims (tid&3)*16..+15
      int j = tid >> 2, d0 = (tid & 3) * 16;
      const float* src = qkv + (size_t)(b*TT + kt*64 + j) * C3 + CC + h*HD + d0;
      u16* kp = &Ks[j * LDP + d0];
      #pragma unroll
      for (int i = 0; i < 16; i += 2){
        u16 a0, a1, b0, b1;
        split2h(src[i], a0, a1);
        split2h(src[i+1], b0, b1);
        *(u32*)&kp[i]      = (u32)a0 | ((u32)b0 << 16);
        *(u32*)&kp[64 + i] = (u32)a1 | ((u32)b1 << 16);
      }
      // stage V transposed [dim][v0|v1]: thread -> dim tid&63, keys (tid>>6)*16..+15
      int d = tid & 63, kp0 = (tid >> 6) * 16;
      const float* vsrc = qkv + (size_t)(b*TT + kt*64 + kp0) * C3 + 2*CC + h*HD + d;
      u16* vt = &Vt[d * LDP];
      #pragma unroll
      for (int i = 0; i < 16; i += 2){
        u16 a0, a1, b0, b1;
        split2h(vsrc[(size_t)i * C3], a0, a1);
        split2h(vsrc[(size_t)(i+1) * C3], b0, b1);
        *(u32*)&vt[kp0 + i]      = (u32)a0 | ((u32)b0 << 16);
        *(u32*)&vt[64 + kp0 + i] = (u32)a1 | ((u32)b1 << 16);
      }
    }
    __syncthreads();
    // S = Q K^T (x4096)
    floatx4 S[4] = {};
    #pragma unroll
    for (int ks = 0; ks < 6; ++ks){
      short8 fa = *(const short8*)&Qs[(m0 + el) * LDP + ABase[ks] + eq*8];
      short8 fb[4];
      #pragma unroll
      for (int nt = 0; nt < 4; ++nt)
        fb[nt] = *(const short8*)&Ks[(nt*16 + el) * LDP + BBase[ks] + eq*8];
      #pragma unroll
      for (int nt = 0; nt < 4; ++nt)
        S[nt] = __builtin_amdgcn_mfma_f32_16x16x32_f16(fa, fb[nt], S[nt], 0, 0, 0);
    }
    // mask + online softmax (16 rows per wave; m row-uniform via shfl over el)
    #pragma unroll
    for (int nt = 0; nt < 4; ++nt){
      int kcol = kt*64 + nt*16 + el;
      #pragma unroll
      for (int r = 0; r < 4; ++r){
        int grow = row0 + m0 + eq*4 + r;
        float sv = S[nt][r] * cmul;
        S[nt][r] = (kcol <= grow) ? sv : -1e30f;
      }
    }
    #pragma unroll
    for (int r = 0; r < 4; ++r){
      float tmax = fmaxf(fmaxf(S[0][r], S[1][r]), fmaxf(S[2][r], S[3][r]));
      #pragma unroll
      for (int off = 1; off < 16; off <<= 1) tmax = fmaxf(tmax, __shfl_xor(tmax, off));
      float mnew = fmaxf(mrow[r], tmax);
      float al = exp2f(mrow[r] - mnew);
      mrow[r] = mnew;
      lrow[r] *= al;
      #pragma unroll
      for (int nt = 0; nt < 4; ++nt) O[nt][r] *= al;
      #pragma unroll
      for (int nt = 0; nt < 4; ++nt){
        float p = exp2f(S[nt][r] - mnew);
        lrow[r] += p;
        S[nt][r] = p;
      }
    }
    // write P (x64, 2-split) into wave-private Ps rows
    #pragma unroll
    for (int nt = 0; nt < 4; ++nt){
      #pragma unroll
      for (int r = 0; r < 4; ++r){
        u16 p0, p1; split2h(S[nt][r], p0, p1);
        int rowl = m0 + eq*4 + r;
        Ps[rowl * LDP + nt*16 + el] = p0;
        Ps[rowl * LDP + 64 + nt*16 + el] = p1;
      }
    }
    // O += P V (P x64, V x64)
    #pragma unroll
    for (int ks = 0; ks < 6; ++ks){
      short8 fa = *(const short8*)&Ps[(m0 + el) * LDP + ABase[ks] + eq*8];
      short8 fb[4];
      #pragma unroll
      for (int nt = 0; nt < 4; ++nt)
        fb[nt] = *(const short8*)&Vt[(nt*16 + el) * LDP + BBase[ks] + eq*8];
      #pragma unroll
      for (int nt = 0; nt < 4; ++nt)
        O[nt] = __builtin_amdgcn_mfma_f32_16x16x32_f16(fa, fb[nt], O[nt], 0, 0, 0);
    }
  }
  // epilogue: reduce l over el lanes, normalize (O is x4096), write yH 2-split
  #pragma unroll
  for (int r = 0; r < 4; ++r){
    float l = lrow[r];
    #pragma unroll
    for (int off = 1; off < 16; off <<= 1) l += __shfl_xor(l, off);
    float inv = 1.f / (l * 4096.f);
    int grow = row0 + m0 + eq*4 + r;
    u16* dst = yH + (size_t)(b*TT + grow) * LDA2 + h*HD;
    #pragma unroll
    for (int nt = 0; nt < 4; ++nt){
      float yv = O[nt][r] * inv;
      u16 y0, y1; split2h(yv, y0, y1);
      dst[nt*16 + el] = y0;
      dst[768 + nt*16 + el] = y1;
    }
  }
}

// ---------------- router: fp32 logits, softmax, top-2 ----------------
__global__ __launch_bounds__(256) void router_kernel(const float* __restrict__ xn2,
    const float* __restrict__ Wr, int* __restrict__ eids, float* __restrict__ wts)
{
  int wave = threadIdx.x >> 6, lane = threadIdx.x & 63;
  int tok = blockIdx.x * 4 + wave;
  int g = lane >> 4, e = lane & 15;
  const float* xr = xn2 + (size_t)tok * CC;
  float s = 0.f;
  for (int c4 = 0; c4 < 192; ++c4){
    int c = c4 * 4 + g;
    s += xr[c] * Wr[c * EE + e];
  }
  s += __shfl_xor(s, 16);
  s += __shfl_xor(s, 32);
  float mx = s;
  #pragma unroll
  for (int off = 1; off < 16; off <<= 1) mx = fmaxf(mx, __shfl_xor(mx, off));
  float p = expf(s - mx);
  float Z = p;
  #pragma unroll
  for (int off = 1; off < 16; off <<= 1) Z += __shfl_xor(Z, off);
  p /= Z;
  float best = -1.f; int bi = 0;
  for (int ee = 0; ee < 16; ++ee){
    float pe = __shfl(p, ee);
    if (pe > best){ best = pe; bi = ee; }
  }
  float sec = -1.f; int si = 0;
  for (int ee = 0; ee < 16; ++ee){
    float pe = __shfl(p, ee);
    if (ee != bi && pe > sec){ sec = pe; si = ee; }
  }
  if (lane == 0){
    eids[tok*2] = bi;  eids[tok*2+1] = si;
    wts [tok*2] = best; wts[tok*2+1] = sec;
  }
}

__global__ __launch_bounds__(256) void moe_count(const int* __restrict__ eids,
    int* __restrict__ counts, int* __restrict__ offs, int* __restrict__ curs)
{
  __shared__ int lc[EE];
  int tid = threadIdx.x;
  if (tid < EE) lc[tid] = 0;
  __syncthreads();
  for (int i = tid; i < NSLOT; i += 256) atomicAdd(&lc[eids[i]], 1);
  __syncthreads();
  if (tid == 0){
    int run = 0;
    for (int e = 0; e < EE; ++e){
      counts[e] = lc[e]; offs[e] = run; curs[e] = run; run += lc[e];
    }
    offs[EE] = run;
  }
}

__global__ __launch_bounds__(256) void moe_scatter(const int* __restrict__ eids,
    const float* __restrict__ wts, int* __restrict__ curs,
    int* __restrict__ rowmap, float* __restrict__ wgtm)
{
  int i = blockIdx.x * 256 + threadIdx.x;
  int e = eids[i];
  int pos = atomicAdd(&curs[e], 1);
  rowmap[pos] = i >> 1;
  wgtm[pos] = wts[i];
}

__global__ __launch_bounds__(256) void add2(const float* __restrict__ a,
    const float* __restrict__ b, float* __restrict__ o, int n)
{
  int i = blockIdx.x * 256 + threadIdx.x;
  if (i < n) o[i] = a[i] + b[i];
}

// ---------------- MoE expert GEMM1: H = gelu(gather(xn2b) @ W1t^T + b1) --------------
// T4 depth-2 pipeline (3 buffers, counted vmcnt).
__global__ __launch_bounds__(256) void gemm_moe1(
    const u16* __restrict__ Xb, const u16* __restrict__ W1t, const float* __restrict__ b1,
    u16* __restrict__ H, const int* __restrict__ counts, const int* __restrict__ offs,
    const int* __restrict__ rowmap)
{
  int e = blockIdx.z;
  int cnt = counts[e];
  int m0 = blockIdx.y * 128;
  if (m0 >= cnt) return;
  int off = offs[e];
  int n0 = blockIdx.x * 128;
  const u16* Bt = W1t + (size_t)e * DFFN * CC;
  __shared__ u16 As[3][128 * 32];
  __shared__ u16 Bs[3][128 * 32];
  int tid = threadIdx.x;
  int lane = tid & 63, wave = tid >> 6;
  int wm = wave & 1, wn = wave >> 1;
  int ra = tid >> 2, ka = (tid & 3) * 8;
  int r0 = m0 + ra, r1i = m0 + ra + 64;
  int rr0 = (r0  < cnt) ? r0  : cnt - 1;   // clamp: rows >= cnt discarded in epilogue
  int rr1 = (r1i < cnt) ? r1i : cnt - 1;
  const u16* pa0 = Xb + (size_t)rowmap[off + rr0] * CC + ka;
  const u16* pa1 = Xb + (size_t)rowmap[off + rr1] * CC + ka;
  const u16* pb0 = Bt + (size_t)(n0 + ra)      * CC + ka;
  const u16* pb1 = Bt + (size_t)(n0 + ra + 64) * CC + ka;
  floatx4 acc[4][4] = {};
  int el = lane & 15, eq = lane >> 4;

  auto stage = [&](int buf, int k0){
    gload_lds16(pa0 + k0, &As[buf][wave*512]);
    gload_lds16(pa1 + k0, &As[buf][2048 + wave*512]);
    gload_lds16(pb0 + k0, &Bs[buf][wave*512]);
    gload_lds16(pb1 + k0, &Bs[buf][2048 + wave*512]);
  };
  const int nsteps = CC / 32;        // 24
  stage(0, 0);
  stage(1, 32);
  int cur = 0;
  for (int i = 0; i < nsteps; ++i){
    __builtin_amdgcn_sched_barrier(0);
    if (i + 1 < nsteps) PIPE_WAIT_STEADY; else PIPE_WAIT_LAST;
    PIPE_BARRIER;
    if (i + 2 < nsteps){
      int nx = cur + 2; if (nx >= 3) nx -= 3;
      stage(nx, (i + 2) * 32);
    }
    short8 fa[4], fb[4];
    #pragma unroll
    for (int t = 0; t < 4; ++t)
      fa[t] = *(const short8*)&As[cur][(size_t)(wm*64 + t*16 + el) * 32 + eq*8];
    #pragma unroll
    for (int t = 0; t < 4; ++t)
      fb[t] = *(const short8*)&Bs[cur][(size_t)(wn*64 + t*16 + el) * 32 + eq*8];
    #pragma unroll
    for (int mt = 0; mt < 4; ++mt)
      #pragma unroll
      for (int nt = 0; nt < 4; ++nt)
        acc[mt][nt] = __builtin_amdgcn_mfma_f32_16x16x32_bf16(fa[mt], fb[nt], acc[mt][nt], 0, 0, 0);
    cur = (cur == 2) ? 0 : cur + 1;
  }
  #pragma unroll
  for (int mt = 0; mt < 4; ++mt){
    #pragma unroll
    for (int nt = 0; nt < 4; ++nt){
      int col = n0 + wn*64 + nt*16 + el;
      float bv = b1[(size_t)e * DFFN + col];
      #pragma unroll
      for (int r = 0; r < 4; ++r){
        int row = m0 + wm*64 + mt*16 + eq*4 + r;
        if (row < cnt)
          H[(size_t)(off + row) * DFFN + col] = f2bf(gelu_exact(acc[mt][nt][r] + bv));
      }
    }
  }
}

// ---------------- MoE expert GEMM2 (K-split x2): out[tok] += w * (H @ W2t^T + b2) ----
// T4 depth-2 pipeline (3 buffers, counted vmcnt).
#define KSPL 2
__global__ __launch_bounds__(256) void gemm_moe2(
    const u16* __restrict__ H, const u16* __restrict__ W2t, const float* __restrict__ b2,
    float* __restrict__ Out, const int* __restrict__ counts, const int* __restrict__ offs,
    const int* __restrict__ rowmap, const float* __restrict__ wgtm)
{
  int e = blockIdx.z;
  int cnt = counts[e];
  int m0 = blockIdx.y * 128;
  if (m0 >= cnt) return;
  int off = offs[e];
  int bx = blockIdx.x;
  int n0 = (bx % 6) * 128;
  int ksp = bx / 6;
  const u16* Bt = W2t + (size_t)e * CC * DFFN;
  __shared__ u16 As[3][128 * 32];
  __shared__ u16 Bs[3][128 * 32];
  int tid = threadIdx.x;
  int lane = tid & 63, wave = tid >> 6;
  int wm = wave & 1, wn = wave >> 1;
  int ra = tid >> 2, ka = (tid & 3) * 8;
  int r0 = m0 + ra, r1i = m0 + ra + 64;
  int rr0 = (r0  < cnt) ? r0  : cnt - 1;
  int rr1 = (r1i < cnt) ? r1i : cnt - 1;
  const u16* pa0 = H + (size_t)(off + rr0) * DFFN + ka;
  const u16* pa1 = H + (size_t)(off + rr1) * DFFN + ka;
  const u16* pb0 = Bt + (size_t)(n0 + ra)      * DFFN + ka;
  const u16* pb1 = Bt + (size_t)(n0 + ra + 64) * DFFN + ka;
  floatx4 acc[4][4] = {};
  int el = lane & 15, eq = lane >> 4;
  int kbeg = ksp * (DFFN / KSPL);

  auto stage = [&](int buf, int k0){
    gload_lds16(pa0 + k0, &As[buf][wave*512]);
    gload_lds16(pa1 + k0, &As[buf][2048 + wave*512]);
    gload_lds16(pb0 + k0, &Bs[buf][wave*512]);
    gload_lds16(pb1 + k0, &Bs[buf][2048 + wave*512]);
  };
  const int nsteps = (DFFN / KSPL) / 32;   // 48
  stage(0, kbeg);
  stage(1, kbeg + 32);
  int cur = 0;
  for (int i = 0; i < nsteps; ++i){
    __builtin_amdgcn_sched_barrier(0);
    if (i + 1 < nsteps) PIPE_WAIT_STEADY; else PIPE_WAIT_LAST;
    PIPE_BARRIER;
    if (i + 2 < nsteps){
      int nx = cur + 2; if (nx >= 3) nx -= 3;
      stage(nx, kbeg + (i + 2) * 32);
    }
    short8 fa[4], fb[4];
    #pragma unroll
    for (int t = 0; t < 4; ++t)
      fa[t] = *(const short8*)&As[cur][(size_t)(wm*64 + t*16 + el) * 32 + eq*8];
    #pragma unroll
    for (int t = 0; t < 4; ++t)
      fb[t] = *(const short8*)&Bs[cur][(size_t)(wn*64 + t*16 + el) * 32 + eq*8];
    #pragma unroll
    for (int mt = 0; mt < 4; ++mt)
      #pragma unroll
      for (int nt = 0; nt < 4; ++nt)
        acc[mt][nt] = __builtin_amdgcn_mfma_f32_16x16x32_bf16(fa[mt], fb[nt], acc[mt][nt], 0, 0, 0);
    cur = (cur == 2) ? 0 : cur + 1;
  }
  #pragma unroll
  for (int mt = 0; mt < 4; ++mt){
    #pragma unroll
    for (int nt = 0; nt < 4; ++nt){
      int col = n0 + wn*64 + nt*16 + el;
      float bv = (ksp == 0) ? b2[(size_t)e * CC + col] : 0.f;
      #pragma unroll
      for (int r = 0; r < 4; ++r){
        int row = m0 + wm*64 + mt*16 + eq*4 + r;
        if (row < cnt){
          int slot = off + row;
          int tok = rowmap[slot];
          float wv = wgtm[slot];
          atomicAdd(&Out[(size_t)tok * CC + col], wv * (acc[mt][nt][r] + bv));
        }
      }
    }
  }
}

// =====================================================================================
extern "C" void kernel_launch(void* const* d_in, const int* in_sizes, int n_in,
                              void* d_out, int out_size, void* d_ws, size_t ws_size,
                              hipStream_t stream)
{
  const float* x     = (const float*)d_in[0];
  const float* ln1w  = (const float*)d_in[1];
  const float* ln1b  = (const float*)d_in[2];
  const float* Wattn = (const float*)d_in[3];
  const float* battn = (const float*)d_in[4];
  const float* Wproj = (const float*)d_in[5];
  const float* bproj = (const float*)d_in[6];
  const float* ln2w  = (const float*)d_in[7];
  const float* ln2b  = (const float*)d_in[8];
  const float* Wrout = (const float*)d_in[9];
  const float* W1    = (const float*)d_in[10];
  const float* b1    = (const float*)d_in[11];
  const float* W2    = (const float*)d_in[12];
  const float* b2    = (const float*)d_in[13];
  float* out = (float*)d_out;

  char* w = (char*)d_ws;
  auto alloc = [&](size_t bytes)->char* {
    char* p = w; w += (bytes + 255) & ~(size_t)255; return p;
  };
  u16* watp  = (u16*)alloc((size_t)C3 * LDA2 * 2);      //  7.1 MB  fp16 2-split [N][1536]
  u16* wptp  = (u16*)alloc((size_t)CC * LDA2 * 2);      //  2.4 MB
  u16* w1t   = (u16*)alloc((size_t)EE * DFFN * CC * 2); // 75.5 MB  bf16
  u16* w2t   = (u16*)alloc((size_t)EE * CC * DFFN * 2); // 75.5 MB
  u16* xH    = (u16*)alloc((size_t)NTOK * LDA2 * 2);    // 12.6 MB  LN1 out, fp16 2-split
  float* qkv = (float*)alloc((size_t)NTOK * C3 * 4);    // 37.7 MB
  u16* yH    = (u16*)alloc((size_t)NTOK * LDA2 * 2);    // 12.6 MB  attn out, fp16 2-split
  u16* Hbuf  = (u16*)alloc((size_t)NSLOT * DFFN * 2);   // 50.3 MB
  float* x2    = (float*)alloc((size_t)NTOK * CC * 4);
  float* xn2   = (float*)alloc((size_t)NTOK * CC * 4);
  u16*   xn2b  = (u16*)alloc((size_t)NTOK * CC * 2);
  int*   eids  = (int*)alloc(NSLOT * 4);
  float* wts   = (float*)alloc(NSLOT * 4);
  int* counts  = (int*)alloc(256);
  int* offs    = (int*)alloc(256);
  int* curs    = (int*)alloc(256);
  int* rowmap  = (int*)alloc(NSLOT * 4);
  float* wgtm  = (float*)alloc(NSLOT * 4);

  // 1) weight conversion
  hipLaunchKernelGGL((transpose_split<1>), dim3(C3/32, CC/32, 1), dim3(256), 0, stream,
                     Wattn, watp, CC, C3);
  hipLaunchKernelGGL((transpose_split<1>), dim3(CC/32, CC/32, 1), dim3(256), 0, stream,
                     Wproj, wptp, CC, CC);
  hipLaunchKernelGGL((transpose_split<0>), dim3(DFFN/32, CC/32, EE), dim3(256), 0, stream,
                     W1, w1t, CC, DFFN);
  hipLaunchKernelGGL((transpose_split<0>), dim3(CC/32, DFFN/32, EE), dim3(256), 0, stream,
                     W2, w2t, DFFN, CC);
  // 2) LN1 -> fp16 2-split xH
  hipLaunchKernelGGL((ln_kernel<1>), dim3(NTOK), dim3(256), 0, stream,
                     x, ln1w, ln1b, (float*)nullptr, xH);
  // 3) qkv = xn @ W_attn + b_attn (single K=2304 fp16 3-term pass, T4 pipeline)
  hipLaunchKernelGGL(gemm_dense, dim3(C3/128, NTOK/128), dim3(256), 0, stream,
                     xH, watp, qkv, battn, (const float*)nullptr, C3);
  // 4) MFMA flash attention (Q-tile 64, 2 blocks/CU) -> yH (fp16 2-split)
  hipLaunchKernelGGL(flash_mfma, dim3(16, BB*HH), dim3(256), 0, stream, qkv, yH);
  // 5) x2 = x + y @ W_proj + b_proj (residual folded into epilogue)
  hipLaunchKernelGGL(gemm_dense, dim3(CC/128, NTOK/128), dim3(256), 0, stream,
                     yH, wptp, x2, bproj, x, CC);
  // 6) LN2 -> xn2 fp32 (router) + bf16 (MoE input)
  hipLaunchKernelGGL((ln_kernel<0>), dim3(NTOK), dim3(256), 0, stream,
                     x2, ln2w, ln2b, xn2, xn2b);
  // 7) router + expert gather lists
  hipLaunchKernelGGL(router_kernel, dim3(NTOK/4), dim3(256), 0, stream, xn2, Wrout, eids, wts);
  hipLaunchKernelGGL(moe_count, dim3(1), dim3(256), 0, stream, eids, counts, offs, curs);
  hipLaunchKernelGGL(moe_scatter, dim3(NSLOT/256), dim3(256), 0, stream, eids, wts, curs, rowmap, wgtm);
  // 8) out = x2 + xn2
  hipLaunchKernelGGL(add2, dim3(NTOK*CC/256), dim3(256), 0, stream, x2, xn2, out, NTOK*CC);
  // 9) MoE expert FFN
  hipLaunchKernelGGL(gemm_moe1, dim3(DFFN/128, 32, EE), dim3(256), 0, stream,
                     xn2b, w1t, b1, Hbuf, counts, offs, rowmap);
  hipLaunchKernelGGL(gemm_moe2, dim3(6*KSPL, 32, EE), dim3(256), 0, stream,
                     Hbuf, w2t, b2, out, counts, offs, rowmap, wgtm);
}

// Round 3
// 909.609 us; speedup vs baseline: 1.0612x; 1.0489x over previous
//
#include <hip/hip_runtime.h>
#include <math.h>

#define CC    768
#define C3    2304
#define KD    2304   /* dense GEMM K: 3 chunks x 768 (fp16 3-term split) */
#define LDA2  1536   /* compact 2-split row stride: [a0(768) | a1(768)] */
#define TT    1024
#define BB    4
#define HH    12
#define HD    64
#define EE    16
#define DFFN  3072
#define NTOK  4096
#define NSLOT 8192
#define LDP   136    /* flash LDS padded stride (halves) */

typedef unsigned short u16;
typedef unsigned int   u32;
typedef __attribute__((ext_vector_type(8))) short short8;
typedef __attribute__((ext_vector_type(4))) float floatx4;

__device__ __forceinline__ u16 f2bf(float f){
  u32 x = __builtin_bit_cast(u32, f);
  x += 0x7fffu + ((x >> 16) & 1u);   // RNE
  return (u16)(x >> 16);
}
__device__ __forceinline__ u16 f2h(float f){
  _Float16 h = (_Float16)f;
  return __builtin_bit_cast(u16, h);
}
__device__ __forceinline__ float h2f(u16 u){
  return (float)__builtin_bit_cast(_Float16, u);
}
__device__ __forceinline__ float gelu_exact(float v){
  return 0.5f * v * (1.f + erff(v * 0.70710678118654752440f));
}
// x64-scaled fp16 2-way split: v*64 = h0 + h1 (+ <2^-24 rel residual)
__device__ __forceinline__ void split2h(float v, u16& h0, u16& h1){
  float vs = v * 64.f;
  h0 = f2h(vs);
  h1 = f2h(vs - h2f(h0));
}
// async global->LDS, 16B per lane, LDS dest = wave-uniform base + lane*16
__device__ __forceinline__ void gload_lds16(const void* g, void* l){
  __builtin_amdgcn_global_load_lds(
      (const __attribute__((address_space(1))) void*)g,
      (__attribute__((address_space(3))) void*)l, 16, 0, 0);
}

// T4 pipeline fences: counted vmcnt + raw barrier (memory-clobbered so LDS
// accesses cannot cross at compile time).
#define PIPE_WAIT_STEADY  asm volatile("s_waitcnt vmcnt(4) lgkmcnt(0)" ::: "memory")
#define PIPE_WAIT_LAST    asm volatile("s_waitcnt vmcnt(0) lgkmcnt(0)" ::: "memory")
#define PIPE_BARRIER      asm volatile("s_barrier" ::: "memory")

// ---------------- fp32 -> transpose. MODE 0: plain bf16 [z][Cn][R].
// MODE 1: fp16 2-split x64 [Cn][1536] ([b0|b1])
template<int MODE>
__global__ __launch_bounds__(256) void transpose_split(const float* __restrict__ src,
    u16* __restrict__ d0, int R, int Cn)
{
  __shared__ float tile[32][33];
  int z = blockIdx.z;
  const float* s = src + (size_t)z * R * Cn;
  int c0 = blockIdx.x * 32, r0 = blockIdx.y * 32;
  int tx = threadIdx.x & 31, ty = threadIdx.x >> 5;
  #pragma unroll
  for (int j = 0; j < 4; ++j)
    tile[ty + j*8][tx] = s[(size_t)(r0 + ty + j*8) * Cn + c0 + tx];
  __syncthreads();
  #pragma unroll
  for (int j = 0; j < 4; ++j){
    float v = tile[tx][ty + j*8];
    if (MODE == 1){
      u16 h0, h1; split2h(v, h0, h1);
      size_t base = (size_t)(c0 + ty + j*8) * LDA2 + (r0 + tx);
      d0[base] = h0; d0[base + 768] = h1;
    } else {
      d0[(size_t)z * R * Cn + (size_t)(c0 + ty + j*8) * R + r0 + tx] = f2bf(v);
    }
  }
}

// ---------------- LayerNorm. MODE 0: fp32 out + bf16 out (stride CC).
// MODE 1: fp16 2-split x64 out [tok][1536].
template<int MODE>
__global__ __launch_bounds__(256) void ln_kernel(const float* __restrict__ x,
    const float* __restrict__ gw, const float* __restrict__ gb,
    float* __restrict__ of, u16* __restrict__ o0)
{
  int tok = blockIdx.x, tid = threadIdx.x;
  const float* xr = x + (size_t)tok * CC;
  float v0 = xr[tid], v1 = xr[tid + 256], v2 = xr[tid + 512];
  __shared__ float r1[4], r2[4];
  __shared__ float mus, rss;
  float s = v0 + v1 + v2;
  #pragma unroll
  for (int off = 32; off >= 1; off >>= 1) s += __shfl_down(s, off);
  if ((tid & 63) == 0) r1[tid >> 6] = s;
  __syncthreads();
  if (tid == 0) mus = (r1[0] + r1[1] + r1[2] + r1[3]) * (1.f / 768.f);
  __syncthreads();
  float mu = mus;
  float d0 = v0 - mu, d1 = v1 - mu, d2 = v2 - mu;
  float t = d0*d0 + d1*d1 + d2*d2;
  #pragma unroll
  for (int off = 32; off >= 1; off >>= 1) t += __shfl_down(t, off);
  if ((tid & 63) == 0) r2[tid >> 6] = t;
  __syncthreads();
  if (tid == 0) rss = rsqrtf((r2[0] + r2[1] + r2[2] + r2[3]) * (1.f / 768.f) + 1e-5f);
  __syncthreads();
  float rstd = rss;
  float dv[3] = {d0, d1, d2};
  #pragma unroll
  for (int i = 0; i < 3; ++i){
    int c = tid + i * 256;
    float vv = dv[i] * rstd * gw[c] + gb[c];
    if (MODE == 1){
      u16 h0, h1; split2h(vv, h0, h1);
      o0[(size_t)tok * LDA2 + c] = h0;
      o0[(size_t)tok * LDA2 + 768 + c] = h1;
    } else {
      size_t idx = (size_t)tok * CC + c;
      of[idx] = vv;
      o0[idx] = f2bf(vv);
    }
  }
}

// ---------------- dense fp16-split NT GEMM: C[M][N] = (1/4096)*A'B' + bias + resid
// A chunks [a0,a0,a1], B chunks [b0,b1,b0]. K=2304.
// T4 depth-2 pipeline: 3 LDS buffers, stage(i+2) in flight, counted vmcnt(4),
// raw s_barrier (no vmcnt(0) drain in main loop).
__global__ __launch_bounds__(256) void gemm_dense(
    const u16* __restrict__ A, const u16* __restrict__ Bt,
    float* __restrict__ C, const float* __restrict__ bias,
    const float* __restrict__ resid, int N)
{
  __shared__ u16 As[3][128 * 32];
  __shared__ u16 Bs[3][128 * 32];
  int tid = threadIdx.x;
  int lane = tid & 63, wave = tid >> 6;
  int wm = wave & 1, wn = wave >> 1;
  int m0 = blockIdx.y * 128, n0 = blockIdx.x * 128;
  int ra = tid >> 2, ka = (tid & 3) * 8;
  const u16* pa0 = A  + (size_t)(m0 + ra)      * LDA2 + ka;
  const u16* pa1 = A  + (size_t)(m0 + ra + 64) * LDA2 + ka;
  const u16* pb0 = Bt + (size_t)(n0 + ra)      * LDA2 + ka;
  const u16* pb1 = Bt + (size_t)(n0 + ra + 64) * LDA2 + ka;
  floatx4 acc[4][4] = {};
  int el = lane & 15, eq = lane >> 4;

  auto stage = [&](int buf, int k0){
    int ca = (k0 >= 768) ? k0 - 768 : k0;
    int cb = (k0 < 1536) ? k0 : k0 - 1536;
    gload_lds16(pa0 + ca, &As[buf][wave*512]);
    gload_lds16(pa1 + ca, &As[buf][2048 + wave*512]);
    gload_lds16(pb0 + cb, &Bs[buf][wave*512]);
    gload_lds16(pb1 + cb, &Bs[buf][2048 + wave*512]);
  };
  const int nsteps = KD / 32;        // 72
  stage(0, 0);
  stage(1, 32);
  int cur = 0;
  for (int i = 0; i < nsteps; ++i){
    __builtin_amdgcn_sched_barrier(0);
    if (i + 1 < nsteps) PIPE_WAIT_STEADY; else PIPE_WAIT_LAST;
    PIPE_BARRIER;
    if (i + 2 < nsteps){
      int nx = cur + 2; if (nx >= 3) nx -= 3;
      stage(nx, (i + 2) * 32);
    }
    short8 fa[4], fb[4];
    #pragma unroll
    for (int t = 0; t < 4; ++t)
      fa[t] = *(const short8*)&As[cur][(size_t)(wm*64 + t*16 + el) * 32 + eq*8];
    #pragma unroll
    for (int t = 0; t < 4; ++t)
      fb[t] = *(const short8*)&Bs[cur][(size_t)(wn*64 + t*16 + el) * 32 + eq*8];
    #pragma unroll
    for (int mt = 0; mt < 4; ++mt)
      #pragma unroll
      for (int nt = 0; nt < 4; ++nt)
        acc[mt][nt] = __builtin_amdgcn_mfma_f32_16x16x32_f16(fa[mt], fb[nt], acc[mt][nt], 0, 0, 0);
    cur = (cur == 2) ? 0 : cur + 1;
  }
  const float ds = 1.f / 4096.f;
  #pragma unroll
  for (int mt = 0; mt < 4; ++mt){
    #pragma unroll
    for (int nt = 0; nt < 4; ++nt){
      int col = n0 + wn*64 + nt*16 + el;
      float bv = bias ? bias[col] : 0.f;
      #pragma unroll
      for (int r = 0; r < 4; ++r){
        int row = m0 + wm*64 + mt*16 + eq*4 + r;
        size_t idx = (size_t)row * N + col;
        float val = acc[mt][nt][r] * ds + bv;
        if (resid) val += resid[idx];
        C[idx] = val;
      }
    }
  }
}

// ---------------- MFMA flash attention (fp16 3-term split, fp32-class accuracy) ----
// grid (16 qtiles LPT, 48 bh), block 256 = 4 waves x 16 rows. Q-tile 64, K-tile 64.
// LDS 69.6 KB -> 2 blocks/CU.
__global__ __launch_bounds__(256) void flash_mfma(const float* __restrict__ qkv,
    u16* __restrict__ yH)
{
  __shared__ u16 Qs[64 * LDP];
  __shared__ u16 Ks[64 * LDP];
  __shared__ u16 Vt[64 * LDP];
  __shared__ u16 Ps[64 * LDP];
  int tid = threadIdx.x;
  int lane = tid & 63, wv = tid >> 6;
  int qi = 15 - blockIdx.x;              // big tiles dispatch first (LPT)
  int bh = blockIdx.y;
  int b = bh / HH, h = bh % HH;
  int el = lane & 15, eq = lane >> 4;
  int m0 = wv * 16;
  int row0 = qi * 64;

  // stage Q (x64 fp16 2-split): thread -> row tid>>2 (wave-private rows!)
  {
    int r = tid >> 2, d0 = (tid & 3) * 16;
    const float* src = qkv + (size_t)(b*TT + row0 + r) * C3 + h*HD + d0;
    u16* q0 = &Qs[r * LDP + d0];
    #pragma unroll
    for (int i = 0; i < 16; i += 2){
      u16 a0, a1, b0, b1;
      split2h(src[i], a0, a1);
      split2h(src[i+1], b0, b1);
      *(u32*)&q0[i]      = (u32)a0 | ((u32)b0 << 16);
      *(u32*)&q0[64 + i] = (u32)a1 | ((u32)b1 << 16);
    }
  }
  floatx4 O[4] = {};
  float mrow[4], lrow[4];
  #pragma unroll
  for (int r = 0; r < 4; ++r){ mrow[r] = -1e30f; lrow[r] = 0.f; }

  const float cmul = 0.125f * 1.44269504088896340736f / 4096.f; // descale + ln->log2
  const int ABase[6] = {0,32,0,32,64,96};
  const int BBase[6] = {0,32,64,96,0,32};

  for (int kt = 0; kt <= qi; ++kt){
    __syncthreads();
    { // stage K [key][k0|k1]: thread -> key tid>>2, dims (tid&3)*16..+15
      int j = tid >> 2, d0 = (tid & 3) * 16;
      const float* src = qkv + (size_t)(b*TT + kt*64 + j) * C3 + CC + h*HD + d0;
      u16* kp = &Ks[j * LDP + d0];
      #pragma unroll
      for (int i = 0; i < 16; i += 2){
        u16 a0, a1, b0, b1;
        split2h(src[i], a0, a1);
        split2h(src[i+1], b0, b1);
        *(u32*)&kp[i]      = (u32)a0 | ((u32)b0 << 16);
        *(u32*)&kp[64 + i] = (u32)a1 | ((u32)b1 << 16);
      }
      // stage V transposed [dim][v0|v1]: thread -> dim tid&63, keys (tid>>6)*16..+15
      int d = tid & 63, kp0 = (tid >> 6) * 16;
      const float* vsrc = qkv + (size_t)(b*TT + kt*64 + kp0) * C3 + 2*CC + h*HD + d;
      u16* vt = &Vt[d * LDP];
      #pragma unroll
      for (int i = 0; i < 16; i += 2){
        u16 a0, a1, b0, b1;
        split2h(vsrc[(size_t)i * C3], a0, a1);
        split2h(vsrc[(size_t)(i+1) * C3], b0, b1);
        *(u32*)&vt[kp0 + i]      = (u32)a0 | ((u32)b0 << 16);
        *(u32*)&vt[64 + kp0 + i] = (u32)a1 | ((u32)b1 << 16);
      }
    }
    __syncthreads();
    // S = Q K^T (x4096)
    floatx4 S[4] = {};
    #pragma unroll
    for (int ks = 0; ks < 6; ++ks){
      short8 fa = *(const short8*)&Qs[(m0 + el) * LDP + ABase[ks] + eq*8];
      short8 fb[4];
      #pragma unroll
      for (int nt = 0; nt < 4; ++nt)
        fb[nt] = *(const short8*)&Ks[(nt*16 + el) * LDP + BBase[ks] + eq*8];
      #pragma unroll
      for (int nt = 0; nt < 4; ++nt)
        S[nt] = __builtin_amdgcn_mfma_f32_16x16x32_f16(fa, fb[nt], S[nt], 0, 0, 0);
    }
    // mask + online softmax (16 rows per wave; m row-uniform via shfl over el)
    #pragma unroll
    for (int nt = 0; nt < 4; ++nt){
      int kcol = kt*64 + nt*16 + el;
      #pragma unroll
      for (int r = 0; r < 4; ++r){
        int grow = row0 + m0 + eq*4 + r;
        float sv = S[nt][r] * cmul;
        S[nt][r] = (kcol <= grow) ? sv : -1e30f;
      }
    }
    #pragma unroll
    for (int r = 0; r < 4; ++r){
      float tmax = fmaxf(fmaxf(S[0][r], S[1][r]), fmaxf(S[2][r], S[3][r]));
      #pragma unroll
      for (int off = 1; off < 16; off <<= 1) tmax = fmaxf(tmax, __shfl_xor(tmax, off));
      float mnew = fmaxf(mrow[r], tmax);
      float al = exp2f(mrow[r] - mnew);
      mrow[r] = mnew;
      lrow[r] *= al;
      #pragma unroll
      for (int nt = 0; nt < 4; ++nt) O[nt][r] *= al;
      #pragma unroll
      for (int nt = 0; nt < 4; ++nt){
        float p = exp2f(S[nt][r] - mnew);
        lrow[r] += p;
        S[nt][r] = p;
      }
    }
    // write P (x64, 2-split) into wave-private Ps rows
    #pragma unroll
    for (int nt = 0; nt < 4; ++nt){
      #pragma unroll
      for (int r = 0; r < 4; ++r){
        u16 p0, p1; split2h(S[nt][r], p0, p1);
        int rowl = m0 + eq*4 + r;
        Ps[rowl * LDP + nt*16 + el] = p0;
        Ps[rowl * LDP + 64 + nt*16 + el] = p1;
      }
    }
    // O += P V (P x64, V x64)
    #pragma unroll
    for (int ks = 0; ks < 6; ++ks){
      short8 fa = *(const short8*)&Ps[(m0 + el) * LDP + ABase[ks] + eq*8];
      short8 fb[4];
      #pragma unroll
      for (int nt = 0; nt < 4; ++nt)
        fb[nt] = *(const short8*)&Vt[(nt*16 + el) * LDP + BBase[ks] + eq*8];
      #pragma unroll
      for (int nt = 0; nt < 4; ++nt)
        O[nt] = __builtin_amdgcn_mfma_f32_16x16x32_f16(fa, fb[nt], O[nt], 0, 0, 0);
    }
  }
  // epilogue: reduce l over el lanes, normalize (O is x4096), write yH 2-split
  #pragma unroll
  for (int r = 0; r < 4; ++r){
    float l = lrow[r];
    #pragma unroll
    for (int off = 1; off < 16; off <<= 1) l += __shfl_xor(l, off);
    float inv = 1.f / (l * 4096.f);
    int grow = row0 + m0 + eq*4 + r;
    u16* dst = yH + (size_t)(b*TT + grow) * LDA2 + h*HD;
    #pragma unroll
    for (int nt = 0; nt < 4; ++nt){
      float yv = O[nt][r] * inv;
      u16 y0, y1; split2h(yv, y0, y1);
      dst[nt*16 + el] = y0;
      dst[768 + nt*16 + el] = y1;
    }
  }
}

// ---------------- router: fp32 logits, softmax, top-2 ----------------
__global__ __launch_bounds__(256) void router_kernel(const float* __restrict__ xn2,
    const float* __restrict__ Wr, int* __restrict__ eids, float* __restrict__ wts)
{
  int wave = threadIdx.x >> 6, lane = threadIdx.x & 63;
  int tok = blockIdx.x * 4 + wave;
  int g = lane >> 4, e = lane & 15;
  const float* xr = xn2 + (size_t)tok * CC;
  float s = 0.f;
  for (int c4 = 0; c4 < 192; ++c4){
    int c = c4 * 4 + g;
    s += xr[c] * Wr[c * EE + e];
  }
  s += __shfl_xor(s, 16);
  s += __shfl_xor(s, 32);
  float mx = s;
  #pragma unroll
  for (int off = 1; off < 16; off <<= 1) mx = fmaxf(mx, __shfl_xor(mx, off));
  float p = expf(s - mx);
  float Z = p;
  #pragma unroll
  for (int off = 1; off < 16; off <<= 1) Z += __shfl_xor(Z, off);
  p /= Z;
  float best = -1.f; int bi = 0;
  for (int ee = 0; ee < 16; ++ee){
    float pe = __shfl(p, ee);
    if (pe > best){ best = pe; bi = ee; }
  }
  float sec = -1.f; int si = 0;
  for (int ee = 0; ee < 16; ++ee){
    float pe = __shfl(p, ee);
    if (ee != bi && pe > sec){ sec = pe; si = ee; }
  }
  if (lane == 0){
    eids[tok*2] = bi;  eids[tok*2+1] = si;
    wts [tok*2] = best; wts[tok*2+1] = sec;
  }
}

__global__ __launch_bounds__(256) void moe_count(const int* __restrict__ eids,
    int* __restrict__ counts, int* __restrict__ offs, int* __restrict__ curs)
{
  __shared__ int lc[EE];
  int tid = threadIdx.x;
  if (tid < EE) lc[tid] = 0;
  __syncthreads();
  for (int i = tid; i < NSLOT; i += 256) atomicAdd(&lc[eids[i]], 1);
  __syncthreads();
  if (tid == 0){
    int run = 0;
    for (int e = 0; e < EE; ++e){
      counts[e] = lc[e]; offs[e] = run; curs[e] = run; run += lc[e];
    }
    offs[EE] = run;
  }
}

// scatter also records the inverse map slot := invmap[tok*2+k] for the finalize gather
__global__ __launch_bounds__(256) void moe_scatter(const int* __restrict__ eids,
    const float* __restrict__ wts, int* __restrict__ curs,
    int* __restrict__ rowmap, int* __restrict__ invmap)
{
  int i = blockIdx.x * 256 + threadIdx.x;
  int e = eids[i];
  int pos = atomicAdd(&curs[e], 1);
  rowmap[pos] = i >> 1;
  invmap[i] = pos;
}

// ---------------- MoE expert GEMM1: H = gelu(gather(xn2b) @ W1t^T + b1) --------------
// T4 depth-2 pipeline (3 buffers, counted vmcnt).
__global__ __launch_bounds__(256) void gemm_moe1(
    const u16* __restrict__ Xb, const u16* __restrict__ W1t, const float* __restrict__ b1,
    u16* __restrict__ H, const int* __restrict__ counts, const int* __restrict__ offs,
    const int* __restrict__ rowmap)
{
  int e = blockIdx.z;
  int cnt = counts[e];
  int m0 = blockIdx.y * 128;
  if (m0 >= cnt) return;
  int off = offs[e];
  int n0 = blockIdx.x * 128;
  const u16* Bt = W1t + (size_t)e * DFFN * CC;
  __shared__ u16 As[3][128 * 32];
  __shared__ u16 Bs[3][128 * 32];
  int tid = threadIdx.x;
  int lane = tid & 63, wave = tid >> 6;
  int wm = wave & 1, wn = wave >> 1;
  int ra = tid >> 2, ka = (tid & 3) * 8;
  int r0 = m0 + ra, r1i = m0 + ra + 64;
  int rr0 = (r0  < cnt) ? r0  : cnt - 1;   // clamp: rows >= cnt discarded in epilogue
  int rr1 = (r1i < cnt) ? r1i : cnt - 1;
  const u16* pa0 = Xb + (size_t)rowmap[off + rr0] * CC + ka;
  const u16* pa1 = Xb + (size_t)rowmap[off + rr1] * CC + ka;
  const u16* pb0 = Bt + (size_t)(n0 + ra)      * CC + ka;
  const u16* pb1 = Bt + (size_t)(n0 + ra + 64) * CC + ka;
  floatx4 acc[4][4] = {};
  int el = lane & 15, eq = lane >> 4;

  auto stage = [&](int buf, int k0){
    gload_lds16(pa0 + k0, &As[buf][wave*512]);
    gload_lds16(pa1 + k0, &As[buf][2048 + wave*512]);
    gload_lds16(pb0 + k0, &Bs[buf][wave*512]);
    gload_lds16(pb1 + k0, &Bs[buf][2048 + wave*512]);
  };
  const int nsteps = CC / 32;        // 24
  stage(0, 0);
  stage(1, 32);
  int cur = 0;
  for (int i = 0; i < nsteps; ++i){
    __builtin_amdgcn_sched_barrier(0);
    if (i + 1 < nsteps) PIPE_WAIT_STEADY; else PIPE_WAIT_LAST;
    PIPE_BARRIER;
    if (i + 2 < nsteps){
      int nx = cur + 2; if (nx >= 3) nx -= 3;
      stage(nx, (i + 2) * 32);
    }
    short8 fa[4], fb[4];
    #pragma unroll
    for (int t = 0; t < 4; ++t)
      fa[t] = *(const short8*)&As[cur][(size_t)(wm*64 + t*16 + el) * 32 + eq*8];
    #pragma unroll
    for (int t = 0; t < 4; ++t)
      fb[t] = *(const short8*)&Bs[cur][(size_t)(wn*64 + t*16 + el) * 32 + eq*8];
    #pragma unroll
    for (int mt = 0; mt < 4; ++mt)
      #pragma unroll
      for (int nt = 0; nt < 4; ++nt)
        acc[mt][nt] = __builtin_amdgcn_mfma_f32_16x16x32_bf16(fa[mt], fb[nt], acc[mt][nt], 0, 0, 0);
    cur = (cur == 2) ? 0 : cur + 1;
  }
  #pragma unroll
  for (int mt = 0; mt < 4; ++mt){
    #pragma unroll
    for (int nt = 0; nt < 4; ++nt){
      int col = n0 + wn*64 + nt*16 + el;
      float bv = b1[(size_t)e * DFFN + col];
      #pragma unroll
      for (int r = 0; r < 4; ++r){
        int row = m0 + wm*64 + mt*16 + eq*4 + r;
        if (row < cnt)
          H[(size_t)(off + row) * DFFN + col] = f2bf(gelu_exact(acc[mt][nt][r] + bv));
      }
    }
  }
}

// ---------------- MoE expert GEMM2 (K-split x2): Y[ksp][slot] = H @ W2t^T (+b2) ------
// T4 depth-2 pipeline (3 buffers, counted vmcnt). PLAIN STORES (no atomics):
// every (ksp, slot) cell written exactly once; finalize does the weighted gather-sum.
#define KSPL 2
__global__ __launch_bounds__(256) void gemm_moe2(
    const u16* __restrict__ H, const u16* __restrict__ W2t, const float* __restrict__ b2,
    float* __restrict__ Y, const int* __restrict__ counts, const int* __restrict__ offs)
{
  int e = blockIdx.z;
  int cnt = counts[e];
  int m0 = blockIdx.y * 128;
  if (m0 >= cnt) return;
  int off = offs[e];
  int bx = blockIdx.x;
  int n0 = (bx % 6) * 128;
  int ksp = bx / 6;
  const u16* Bt = W2t + (size_t)e * CC * DFFN;
  __shared__ u16 As[3][128 * 32];
  __shared__ u16 Bs[3][128 * 32];
  int tid = threadIdx.x;
  int lane = tid & 63, wave = tid >> 6;
  int wm = wave & 1, wn = wave >> 1;
  int ra = tid >> 2, ka = (tid & 3) * 8;
  int r0 = m0 + ra, r1i = m0 + ra + 64;
  int rr0 = (r0  < cnt) ? r0  : cnt - 1;
  int rr1 = (r1i < cnt) ? r1i : cnt - 1;
  const u16* pa0 = H + (size_t)(off + rr0) * DFFN + ka;
  const u16* pa1 = H + (size_t)(off + rr1) * DFFN + ka;
  const u16* pb0 = Bt + (size_t)(n0 + ra)      * DFFN + ka;
  const u16* pb1 = Bt + (size_t)(n0 + ra + 64) * DFFN + ka;
  floatx4 acc[4][4] = {};
  int el = lane & 15, eq = lane >> 4;
  int kbeg = ksp * (DFFN / KSPL);

  auto stage = [&](int buf, int k0){
    gload_lds16(pa0 + k0, &As[buf][wave*512]);
    gload_lds16(pa1 + k0, &As[buf][2048 + wave*512]);
    gload_lds16(pb0 + k0, &Bs[buf][wave*512]);
    gload_lds16(pb1 + k0, &Bs[buf][2048 + wave*512]);
  };
  const int nsteps = (DFFN / KSPL) / 32;   // 48
  stage(0, kbeg);
  stage(1, kbeg + 32);
  int cur = 0;
  for (int i = 0; i < nsteps; ++i){
    __builtin_amdgcn_sched_barrier(0);
    if (i + 1 < nsteps) PIPE_WAIT_STEADY; else PIPE_WAIT_LAST;
    PIPE_BARRIER;
    if (i + 2 < nsteps){
      int nx = cur + 2; if (nx >= 3) nx -= 3;
      stage(nx, kbeg + (i + 2) * 32);
    }
    short8 fa[4], fb[4];
    #pragma unroll
    for (int t = 0; t < 4; ++t)
      fa[t] = *(const short8*)&As[cur][(size_t)(wm*64 + t*16 + el) * 32 + eq*8];
    #pragma unroll
    for (int t = 0; t < 4; ++t)
      fb[t] = *(const short8*)&Bs[cur][(size_t)(wn*64 + t*16 + el) * 32 + eq*8];
    #pragma unroll
    for (int mt = 0; mt < 4; ++mt)
      #pragma unroll
      for (int nt = 0; nt < 4; ++nt)
        acc[mt][nt] = __builtin_amdgcn_mfma_f32_16x16x32_bf16(fa[mt], fb[nt], acc[mt][nt], 0, 0, 0);
    cur = (cur == 2) ? 0 : cur + 1;
  }
  #pragma unroll
  for (int mt = 0; mt < 4; ++mt){
    #pragma unroll
    for (int nt = 0; nt < 4; ++nt){
      int col = n0 + wn*64 + nt*16 + el;
      float bv = (ksp == 0) ? b2[(size_t)e * CC + col] : 0.f;
      #pragma unroll
      for (int r = 0; r < 4; ++r){
        int row = m0 + wm*64 + mt*16 + eq*4 + r;
        if (row < cnt)
          Y[((size_t)ksp * NSLOT + off + row) * CC + col] = acc[mt][nt][r] + bv;
      }
    }
  }
}

// ---------------- finalize: out = x2 + xn2 + sum_k w_k * (Y[0][slot_k] + Y[1][slot_k])
__global__ __launch_bounds__(256) void moe_finalize(const float* __restrict__ x2,
    const float* __restrict__ xn2, const float* __restrict__ Y,
    const int* __restrict__ invmap, const float* __restrict__ wts,
    float* __restrict__ out)
{
  int t = blockIdx.x, tid = threadIdx.x;
  int s0 = invmap[t*2], s1 = invmap[t*2 + 1];
  float w0 = wts[t*2],  w1 = wts[t*2 + 1];
  const float* y00 = Y + (size_t)s0 * CC;
  const float* y01 = Y + ((size_t)NSLOT + s0) * CC;
  const float* y10 = Y + (size_t)s1 * CC;
  const float* y11 = Y + ((size_t)NSLOT + s1) * CC;
  size_t base = (size_t)t * CC;
  #pragma unroll
  for (int i = 0; i < 3; ++i){
    int c = tid + i * 256;
    out[base + c] = x2[base + c] + xn2[base + c]
                  + w0 * (y00[c] + y01[c]) + w1 * (y10[c] + y11[c]);
  }
}

// =====================================================================================
extern "C" void kernel_launch(void* const* d_in, const int* in_sizes, int n_in,
                              void* d_out, int out_size, void* d_ws, size_t ws_size,
                              hipStream_t stream)
{
  const float* x     = (const float*)d_in[0];
  const float* ln1w  = (const float*)d_in[1];
  const float* ln1b  = (const float*)d_in[2];
  const float* Wattn = (const float*)d_in[3];
  const float* battn = (const float*)d_in[4];
  const float* Wproj = (const float*)d_in[5];
  const float* bproj = (const float*)d_in[6];
  const float* ln2w  = (const float*)d_in[7];
  const float* ln2b  = (const float*)d_in[8];
  const float* Wrout = (const float*)d_in[9];
  const float* W1    = (const float*)d_in[10];
  const float* b1    = (const float*)d_in[11];
  const float* W2    = (const float*)d_in[12];
  const float* b2    = (const float*)d_in[13];
  float* out = (float*)d_out;

  char* w = (char*)d_ws;
  auto alloc = [&](size_t bytes)->char* {
    char* p = w; w += (bytes + 255) & ~(size_t)255; return p;
  };
  u16* watp  = (u16*)alloc((size_t)C3 * LDA2 * 2);      //  7.1 MB  fp16 2-split [N][1536]
  u16* wptp  = (u16*)alloc((size_t)CC * LDA2 * 2);      //  2.4 MB
  u16* w1t   = (u16*)alloc((size_t)EE * DFFN * CC * 2); // 75.5 MB  bf16
  u16* w2t   = (u16*)alloc((size_t)EE * CC * DFFN * 2); // 75.5 MB
  u16* xH    = (u16*)alloc((size_t)NTOK * LDA2 * 2);    // 12.6 MB  LN1 out, fp16 2-split
  float* qkv = (float*)alloc((size_t)NTOK * C3 * 4);    // 37.7 MB
  u16* yH    = (u16*)alloc((size_t)NTOK * LDA2 * 2);    // 12.6 MB  attn out, fp16 2-split
  u16* Hbuf  = (u16*)alloc((size_t)NSLOT * DFFN * 2);   // 50.3 MB
  float* x2    = (float*)alloc((size_t)NTOK * CC * 4);
  float* xn2   = (float*)alloc((size_t)NTOK * CC * 4);
  u16*   xn2b  = (u16*)alloc((size_t)NTOK * CC * 2);
  int*   eids  = (int*)alloc(NSLOT * 4);
  float* wts   = (float*)alloc(NSLOT * 4);
  int* counts  = (int*)alloc(256);
  int* offs    = (int*)alloc(256);
  int* curs    = (int*)alloc(256);
  int* rowmap  = (int*)alloc(NSLOT * 4);
  int* invmap  = (int*)alloc(NSLOT * 4);
  // Y [KSPL][NSLOT][CC] fp32 = 50,331,648 B overlays xH(12.58 MB)+qkv(37.75 MB),
  // which are both dead before gemm_moe2 runs (xH after QKV gemm, qkv after flash).
  float* Ybuf = (float*)xH;

  // 1) weight conversion
  hipLaunchKernelGGL((transpose_split<1>), dim3(C3/32, CC/32, 1), dim3(256), 0, stream,
                     Wattn, watp, CC, C3);
  hipLaunchKernelGGL((transpose_split<1>), dim3(CC/32, CC/32, 1), dim3(256), 0, stream,
                     Wproj, wptp, CC, CC);
  hipLaunchKernelGGL((transpose_split<0>), dim3(DFFN/32, CC/32, EE), dim3(256), 0, stream,
                     W1, w1t, CC, DFFN);
  hipLaunchKernelGGL((transpose_split<0>), dim3(CC/32, DFFN/32, EE), dim3(256), 0, stream,
                     W2, w2t, DFFN, CC);
  // 2) LN1 -> fp16 2-split xH
  hipLaunchKernelGGL((ln_kernel<1>), dim3(NTOK), dim3(256), 0, stream,
                     x, ln1w, ln1b, (float*)nullptr, xH);
  // 3) qkv = xn @ W_attn + b_attn (single K=2304 fp16 3-term pass, T4 pipeline)
  hipLaunchKernelGGL(gemm_dense, dim3(C3/128, NTOK/128), dim3(256), 0, stream,
                     xH, watp, qkv, battn, (const float*)nullptr, C3);
  // 4) MFMA flash attention (Q-tile 64, 2 blocks/CU) -> yH (fp16 2-split)
  hipLaunchKernelGGL(flash_mfma, dim3(16, BB*HH), dim3(256), 0, stream, qkv, yH);
  // 5) x2 = x + y @ W_proj + b_proj (residual folded into epilogue)
  hipLaunchKernelGGL(gemm_dense, dim3(CC/128, NTOK/128), dim3(256), 0, stream,
                     yH, wptp, x2, bproj, x, CC);
  // 6) LN2 -> xn2 fp32 (router) + bf16 (MoE input)
  hipLaunchKernelGGL((ln_kernel<0>), dim3(NTOK), dim3(256), 0, stream,
                     x2, ln2w, ln2b, xn2, xn2b);
  // 7) router + expert gather lists
  hipLaunchKernelGGL(router_kernel, dim3(NTOK/4), dim3(256), 0, stream, xn2, Wrout, eids, wts);
  hipLaunchKernelGGL(moe_count, dim3(1), dim3(256), 0, stream, eids, counts, offs, curs);
  hipLaunchKernelGGL(moe_scatter, dim3(NSLOT/256), dim3(256), 0, stream, eids, wts, curs, rowmap, invmap);
  // 8) MoE expert FFN (moe2 writes Y with plain stores; no atomics)
  hipLaunchKernelGGL(gemm_moe1, dim3(DFFN/128, 32, EE), dim3(256), 0, stream,
                     xn2b, w1t, b1, Hbuf, counts, offs, rowmap);
  hipLaunchKernelGGL(gemm_moe2, dim3(6*KSPL, 32, EE), dim3(256), 0, stream,
                     Hbuf, w2t, b2, Ybuf, counts, offs);
  // 9) out = x2 + xn2 + weighted expert outputs (absorbs the old add2)
  hipLaunchKernelGGL(moe_finalize, dim3(NTOK), dim3(256), 0, stream,
                     x2, xn2, Ybuf, invmap, wts, out);
}